// Round 4
// baseline (1293.894 us; speedup 1.0000x reference)
//
#include <hip/hip_runtime.h>
#include <hip/hip_bf16.h>

#define DEVI __device__ __forceinline__

using bf16x8 = __attribute__((ext_vector_type(8))) short;   // 8 bf16 in 4 VGPRs (per guide §3)
using f32x4  = __attribute__((ext_vector_type(4))) float;

DEVI unsigned short f2bf(float f) {
    unsigned u = __builtin_bit_cast(unsigned, f);
    return (unsigned short)((u + 0x7FFFu + ((u >> 16) & 1u)) >> 16);
}
DEVI float bf2f(unsigned short h) {
    return __builtin_bit_cast(float, (unsigned)h << 16);
}

DEVI f32x4 mfma16(bf16x8 a, bf16x8 b, f32x4 c) {
    return __builtin_amdgcn_mfma_f32_16x16x32_bf16(a, b, c, 0, 0, 0);
}

// async global->LDS, 16B per lane, LDS dest = wave-uniform base + lane*16 (guide §5)
DEVI void gl16(const void* g, void* l) {
    __builtin_amdgcn_global_load_lds((const __attribute__((address_space(1))) void*)g,
                                     (__attribute__((address_space(3))) void*)l,
                                     16, 0, 0);
}

// ---------------- weight transpose + bf16 cast: WT[n*K+k] = W[k*N+n] ----------------
__global__ void k_transpose(const float* __restrict__ W, unsigned short* __restrict__ WT,
                            int K, int N) {
    long i = (long)blockIdx.x * 256 + threadIdx.x;
    if (i >= (long)K * N) return;
    int nn = (int)(i / K);
    int kk = (int)(i - (long)nn * K);
    WT[i] = f2bf(W[(long)kk * N + nn]);
}

// ---------------- CSR build ----------------
__global__ void k_zero_i32(int* p, int n) {
    int i = blockIdx.x * 256 + threadIdx.x;
    if (i < n) p[i] = 0;
}
__global__ void k_hist(const int* __restrict__ dst, int E, int* __restrict__ deg) {
    int i = blockIdx.x * 256 + threadIdx.x;
    if (i < E) atomicAdd(&deg[dst[i]], 1);
}
__global__ __launch_bounds__(1024)
void k_scan1(const int* __restrict__ deg, int* __restrict__ rp, int* __restrict__ bsum, int n) {
    __shared__ int sh[1024];
    int t = threadIdx.x;
    int i = blockIdx.x * 1024 + t;
    int v = (i < n) ? deg[i] : 0;
    sh[t] = v;
    __syncthreads();
    for (int off = 1; off < 1024; off <<= 1) {
        int y = (t >= off) ? sh[t - off] : 0;
        __syncthreads();
        sh[t] += y;
        __syncthreads();
    }
    if (i < n) rp[i] = sh[t] - v;            // exclusive within block
    if (t == 1023) bsum[blockIdx.x] = sh[1023];
}
__global__ __launch_bounds__(64)
void k_scan2(const int* __restrict__ bsum, int* __restrict__ boff, int nb) {  // nb <= 64
    int lane = threadIdx.x;
    int v = (lane < nb) ? bsum[lane] : 0;
    int x = v;
    for (int off = 1; off < 64; off <<= 1) {
        int y = __shfl_up(x, off);
        if (lane >= off) x += y;
    }
    if (lane < nb) boff[lane] = x - v;
}
__global__ void k_scan3(int* __restrict__ rp, const int* __restrict__ boff,
                        int* __restrict__ cur, int n, int E) {
    int i = blockIdx.x * 256 + threadIdx.x;
    if (i < n) {
        int v = rp[i] + boff[i >> 10];
        rp[i] = v;
        cur[i] = v;
    }
    if (i == 0) rp[n] = E;
}
__global__ void k_fill(const int* __restrict__ src, const int* __restrict__ dst, int E,
                       int* __restrict__ cur, int* __restrict__ esrc) {
    int i = blockIdx.x * 256 + threadIdx.x;
    if (i < E) {
        int d = dst[i];
        int p = atomicAdd(&cur[d], 1);
        esrc[p] = src[i];
    }
}

// ---------------- LayerNorm kernels ----------------
__global__ __launch_bounds__(256)
void k_ln1024_in(const float* __restrict__ x, const float* __restrict__ g,
                 const float* __restrict__ b, unsigned short* __restrict__ out) {
    const long row = blockIdx.x;
    const int tid = threadIdx.x, lane = tid & 63, wid = tid >> 6;
    float4 v = ((const float4*)(x + row * 1024))[tid];
    float s = v.x + v.y + v.z + v.w;
    float s2 = v.x * v.x + v.y * v.y + v.z * v.z + v.w * v.w;
    for (int off = 1; off < 64; off <<= 1) { s += __shfl_xor(s, off); s2 += __shfl_xor(s2, off); }
    __shared__ float red[8];
    if (lane == 0) { red[wid] = s; red[4 + wid] = s2; }
    __syncthreads();
    s = red[0] + red[1] + red[2] + red[3];
    s2 = red[4] + red[5] + red[6] + red[7];
    float m = s * (1.f / 1024.f);
    float var = s2 * (1.f / 1024.f) - m * m;
    float inv = rsqrtf(var + 1e-5f);
    float4 gv = ((const float4*)g)[tid];
    float4 bv = ((const float4*)b)[tid];
    ushort4 o = make_ushort4(f2bf((v.x - m) * inv * gv.x + bv.x),
                             f2bf((v.y - m) * inv * gv.y + bv.y),
                             f2bf((v.z - m) * inv * gv.z + bv.z),
                             f2bf((v.w - m) * inv * gv.w + bv.w));
    ((ushort4*)(out + row * 1024))[tid] = o;
}

__global__ __launch_bounds__(256)
void k_ln1024_out(const float* __restrict__ x, const unsigned short* __restrict__ delta,
                  const float* __restrict__ g, const float* __restrict__ b,
                  float* __restrict__ out) {
    const long row = blockIdx.x;
    const int tid = threadIdx.x, lane = tid & 63, wid = tid >> 6;
    float4 xv = ((const float4*)(x + row * 1024))[tid];
    ushort4 dv = ((const ushort4*)(delta + row * 1024))[tid];
    float4 v;
    v.x = xv.x + bf2f(dv.x);
    v.y = xv.y + bf2f(dv.y);
    v.z = xv.z + bf2f(dv.z);
    v.w = xv.w + bf2f(dv.w);
    float s = v.x + v.y + v.z + v.w;
    float s2 = v.x * v.x + v.y * v.y + v.z * v.z + v.w * v.w;
    for (int off = 1; off < 64; off <<= 1) { s += __shfl_xor(s, off); s2 += __shfl_xor(s2, off); }
    __shared__ float red[8];
    if (lane == 0) { red[wid] = s; red[4 + wid] = s2; }
    __syncthreads();
    s = red[0] + red[1] + red[2] + red[3];
    s2 = red[4] + red[5] + red[6] + red[7];
    float m = s * (1.f / 1024.f);
    float var = s2 * (1.f / 1024.f) - m * m;
    float inv = rsqrtf(var + 1e-5f);
    float4 gv = ((const float4*)g)[tid];
    float4 bv = ((const float4*)b)[tid];
    float4 o;
    o.x = (v.x - m) * inv * gv.x + bv.x;
    o.y = (v.y - m) * inv * gv.y + bv.y;
    o.z = (v.z - m) * inv * gv.z + bv.z;
    o.w = (v.w - m) * inv * gv.w + bv.w;
    ((float4*)(out + row * 1024))[tid] = o;
}

// z-row LN -> ReLU -> residual add into h (fp32 master + bf16 shadow). One wave per row.
__global__ __launch_bounds__(256)
void k_ln256_relu_res(const float* __restrict__ z, const float* __restrict__ g,
                      const float* __restrict__ b, float* __restrict__ hf,
                      unsigned short* __restrict__ hb, int n) {
    int node = blockIdx.x * 4 + (threadIdx.x >> 6);
    if (node >= n) return;
    int lane = threadIdx.x & 63;
    long base = (long)node * 256;
    float4 v = ((const float4*)(z + base))[lane];
    float s = v.x + v.y + v.z + v.w;
    float s2 = v.x * v.x + v.y * v.y + v.z * v.z + v.w * v.w;
    for (int off = 1; off < 64; off <<= 1) { s += __shfl_xor(s, off); s2 += __shfl_xor(s2, off); }
    float m = s * (1.f / 256.f);
    float var = s2 * (1.f / 256.f) - m * m;
    float inv = rsqrtf(var + 1e-5f);
    float4 gv = ((const float4*)g)[lane];
    float4 bv = ((const float4*)b)[lane];
    float4 hv = ((const float4*)(hf + base))[lane];
    float4 o;
    o.x = hv.x + fmaxf((v.x - m) * inv * gv.x + bv.x, 0.f);
    o.y = hv.y + fmaxf((v.y - m) * inv * gv.y + bv.y, 0.f);
    o.z = hv.z + fmaxf((v.z - m) * inv * gv.z + bv.z, 0.f);
    o.w = hv.w + fmaxf((v.w - m) * inv * gv.w + bv.w, 0.f);
    ((float4*)(hf + base))[lane] = o;
    ushort4 ob = make_ushort4(f2bf(o.x), f2bf(o.y), f2bf(o.z), f2bf(o.w));
    ((ushort4*)(hb + base))[lane] = ob;
}

// ---------------- aggregation: z[dst] = h[dst] + sum_{src in-edges} h[src] ----------------
__global__ __launch_bounds__(256)
void k_agg(const float* __restrict__ hf, const unsigned short* __restrict__ hb,
           const int* __restrict__ rp, const int* __restrict__ esrc,
           unsigned short* __restrict__ z, int n) {
    int node = blockIdx.x * 4 + (threadIdx.x >> 6);
    if (node >= n) return;
    int lane = threadIdx.x & 63;
    float4 sv = ((const float4*)(hf + (long)node * 256))[lane];
    float a0 = sv.x, a1 = sv.y, a2 = sv.z, a3 = sv.w;
    int beg = rp[node], end = rp[node + 1];
    for (int e = beg; e < end; ++e) {
        int s = esrc[e];
        ushort4 hv = ((const ushort4*)(hb + (long)s * 256))[lane];
        a0 += bf2f(hv.x);
        a1 += bf2f(hv.y);
        a2 += bf2f(hv.z);
        a3 += bf2f(hv.w);
    }
    ushort4 o = make_ushort4(f2bf(a0), f2bf(a1), f2bf(a2), f2bf(a3));
    ((ushort4*)(z + (long)node * 256))[lane] = o;
}

// ---------------- bf16 MFMA GEMM, 256x256 tile ----------------
// C[M,Nc] = act(A[M,K] @ W + bias), W given as WT[Nc,K].
// BM=BN=256, BK=64, 8 waves (2M x 4N), wave-tile 128x64 (acc 8x4 of 16x16 frags).
// LDS: double-buffered 2 x (A 32KB + B 32KB) = 128 KB, subtile layout:
//   cell(rg = 16-row group 0..15, kg = 8-k group 0..7): [fr 0..15][8 k] bf16
//   elem addr = rg*1024 + kg*128 + fr*8  -> fragment ds_read_b128 at byte
//   rg*2048 + kg*256 + fr*16: 16 lanes spread all 32 banks (2-way = free).
// gl_lds writes linearly (wave base + lane*16B); per-lane GLOBAL src is permuted
// to match (lane -> fr = l&15, kg = kh*4 + (l>>4)), guide m173 pattern.
// Sync: one s_barrier + one vmcnt(0) per K-tile. Stages for tile kt+1 (buf c^1)
// issue at TOP of tile kt; compute reads buf c barrier-free (no writer on c);
// end-of-tile vmcnt(0) drains loads issued a full tile body earlier (cheap),
// barrier publishes them to all waves. Writes to a buffer happen only between
// the barrier ending its readers and the barrier admitting the next readers.
template <int RELU, int WB, int WF>
__global__ __launch_bounds__(512, 2)
void k_gemm256(const unsigned short* __restrict__ A, const unsigned short* __restrict__ WT,
               const float* __restrict__ bias, int M, int K, int Nc,
               unsigned short* __restrict__ outb, float* __restrict__ outf) {
    __shared__ __align__(16) unsigned short lds_a[2 * 16384];
    __shared__ __align__(16) unsigned short lds_b[2 * 16384];
    const int tid = threadIdx.x;
    const int wid = tid >> 6, lane = tid & 63;
    const int fr16 = lane & 15, kg0 = lane >> 4;

    // bijective XCD swizzle (8 XCDs, round-robin dispatch; guide T1/m204)
    const int nwg = gridDim.x;
    const int q = nwg >> 3, r8 = nwg & 7;
    const int xcd = blockIdx.x & 7, sl = blockIdx.x >> 3;
    const int bid = (xcd < r8 ? xcd * (q + 1) : r8 * (q + 1) + (xcd - r8) * q) + sl;

    const int ntN = Nc >> 8;
    const int tM = bid / ntN, tN = bid - tM * ntN;
    const long row0 = (long)tM * 256;
    const int col0 = tN << 8;
    const int wr = wid >> 2, wcn = wid & 3;   // wave tile: rows [wr*128,+128), cols [wcn*64,+64)

    // 8 staging issues per wave per K-tile: j 0..3 = A (rg 2w, 2w+1), j 4..7 = B.
    const unsigned short* gp[8];
    int lo[8];
#pragma unroll
    for (int j = 0; j < 8; ++j) {
        const int rg = 2 * wid + ((j & 3) >> 1);
        const int kh = j & 1;
        long rc;
        if (j < 4) {
            rc = row0 + rg * 16 + fr16;
            if (rc > (long)M - 1) rc = M - 1;
            gp[j] = A + rc * K + (kh * 4 + kg0) * 8;
        } else {
            rc = (long)col0 + rg * 16 + fr16;
            gp[j] = WT + rc * K + (kh * 4 + kg0) * 8;
        }
        lo[j] = rg * 1024 + kh * 512;   // wave-uniform LDS elem offset (HW adds lane*16B)
    }

    f32x4 zero4 = {0.f, 0.f, 0.f, 0.f};
    f32x4 acc[8][4];
#pragma unroll
    for (int m = 0; m < 8; m++)
#pragma unroll
        for (int n = 0; n < 4; n++) acc[m][n] = zero4;

    const int laneRd = kg0 * 128 + fr16 * 8;   // per-lane elem offset within (rg, khalf)

    auto STAGE = [&](int t, int b) {
#pragma unroll
        for (int j = 0; j < 8; ++j) {
            const unsigned short* g = gp[j] + (long)t * 64;
            unsigned short* l = (j < 4 ? lds_a : lds_b) + b * 16384 + lo[j];
            gl16(g, l);
        }
    };
    auto COMPUTE = [&](int c) {
        const int cb = c * 16384;
#pragma unroll
        for (int kk = 0; kk < 2; ++kk) {
            bf16x8 af[8], bfr[4];
#pragma unroll
            for (int m = 0; m < 8; m++)
                af[m] = *(const bf16x8*)&lds_a[cb + (wr * 8 + m) * 1024 + kk * 512 + laneRd];
#pragma unroll
            for (int n = 0; n < 4; n++)
                bfr[n] = *(const bf16x8*)&lds_b[cb + (wcn * 4 + n) * 1024 + kk * 512 + laneRd];
#pragma unroll
            for (int m = 0; m < 8; m++)
#pragma unroll
                for (int n = 0; n < 4; n++) acc[m][n] = mfma16(af[m], bfr[n], acc[m][n]);
        }
    };

    const int nkt = K >> 6;   // K-tiles of 64; K in {256,512,1024} -> 4..16

    STAGE(0, 0);
    asm volatile("s_waitcnt vmcnt(0)" ::: "memory");
    __builtin_amdgcn_s_barrier();

    for (int kt = 0; kt < nkt; ++kt) {
        const int c = kt & 1;
        if (kt + 1 < nkt) STAGE(kt + 1, c ^ 1);
        __builtin_amdgcn_sched_barrier(0);     // pin: stage-issue above this tile's ds_reads
        COMPUTE(c);
        if (kt + 1 < nkt) {
            asm volatile("s_waitcnt vmcnt(0)" ::: "memory");  // drains loads issued ~1 tile ago
            __builtin_amdgcn_s_barrier();
        }
    }

    // epilogue: per 16x16 frag D row = kg0*4 + r, col = fr16
#pragma unroll
    for (int n = 0; n < 4; n++) {
        int col = col0 + wcn * 64 + n * 16 + fr16;
        float bv = bias[col];
#pragma unroll
        for (int m = 0; m < 8; m++) {
            long rb = row0 + wr * 128 + m * 16 + kg0 * 4;
#pragma unroll
            for (int r = 0; r < 4; r++) {
                long rr = rb + r;
                if (rr < M) {
                    float v = acc[m][n][r] + bv;
                    if (RELU) v = fmaxf(v, 0.f);
                    long idx = rr * Nc + col;
                    if (WB) outb[idx] = f2bf(v);
                    if (WF) outf[idx] = v;
                }
            }
        }
    }
}

// ---------------- host orchestration ----------------
extern "C" void kernel_launch(void* const* d_in, const int* in_sizes, int n_in,
                              void* d_out, int out_size, void* d_ws, size_t ws_size,
                              hipStream_t stream) {
    const float* x    = (const float*)d_in[0];
    const int*   eidx = (const int*)d_in[1];
    const float* ln_g = (const float*)d_in[2];
    const float* ln_b = (const float*)d_in[3];
    const float* W1   = (const float*)d_in[4];
    const float* b1   = (const float*)d_in[5];
    const float* W2   = (const float*)d_in[6];
    const float* b2   = (const float*)d_in[7];
    const float* Wa   = (const float*)d_in[8];
    const float* ba   = (const float*)d_in[9];
    const float* Wb   = (const float*)d_in[10];
    const float* bb   = (const float*)d_in[11];
    const float* ng   = (const float*)d_in[12];
    const float* nbt  = (const float*)d_in[13];
    const float* Wd1  = (const float*)d_in[14];
    const float* bd1  = (const float*)d_in[15];
    const float* Wd2  = (const float*)d_in[16];
    const float* bd2  = (const float*)d_in[17];
    const float* outg = (const float*)d_in[18];
    const float* outbeta = (const float*)d_in[19];
    float* out = (float*)d_out;

    const int N = in_sizes[0] / 1024;  // 50000
    const int E = in_sizes[1] / 2;     // 800000
    const int* e_src = eidx;
    const int* e_dst = eidx + E;

    char* ws = (char*)d_ws;
    size_t off = 0;
    auto alloc = [&](size_t bytes) -> char* {
        char* p = ws + off;
        off += (bytes + 255) & ~(size_t)255;
        return p;
    };

    // big multiplexed region: xln (N x 1024 bf16), later {z | za | zbf}, finally delta
    unsigned short* xln = (unsigned short*)alloc((size_t)N * 1024 * 2);
    unsigned short* zb16 = xln;                                          // N*256 bf16
    unsigned short* za   = (unsigned short*)((char*)xln + (size_t)N * 256 * 2);  // N*256 bf16
    float*          zbf  = (float*)((char*)xln + (size_t)N * 256 * 4);   // N*256 f32
    unsigned short* delta = xln;                                         // N*1024 bf16

    unsigned short* h1 = (unsigned short*)alloc((size_t)N * 512 * 2);    // also d1
    float*          hf = (float*)alloc((size_t)N * 256 * 4);
    unsigned short* hb = (unsigned short*)alloc((size_t)N * 256 * 2);

    unsigned short* W1T  = (unsigned short*)alloc((size_t)512 * 1024 * 2);
    unsigned short* W2T  = (unsigned short*)alloc((size_t)256 * 512 * 2);
    unsigned short* WaT  = (unsigned short*)alloc((size_t)3 * 256 * 256 * 2);
    unsigned short* WbT  = (unsigned short*)alloc((size_t)3 * 256 * 256 * 2);
    unsigned short* Wd1T = (unsigned short*)alloc((size_t)512 * 256 * 2);
    unsigned short* Wd2T = (unsigned short*)alloc((size_t)1024 * 512 * 2);

    int* deg  = (int*)alloc((size_t)(N + 1) * 4);
    int* rp   = (int*)alloc((size_t)(N + 1) * 4);
    int* cur  = (int*)alloc((size_t)N * 4);
    int* bsum = (int*)alloc(64 * 4);
    int* boff = (int*)alloc(64 * 4);
    int* esrc = (int*)alloc((size_t)E * 4);

    auto cdiv = [](long a, long b) { return (int)((a + b - 1) / b); };

    // weight prep
    k_transpose<<<cdiv((long)1024 * 512, 256), 256, 0, stream>>>(W1, W1T, 1024, 512);
    k_transpose<<<cdiv((long)512 * 256, 256), 256, 0, stream>>>(W2, W2T, 512, 256);
    for (int i = 0; i < 3; i++) {
        k_transpose<<<cdiv(65536, 256), 256, 0, stream>>>(Wa + (size_t)i * 65536, WaT + (size_t)i * 65536, 256, 256);
        k_transpose<<<cdiv(65536, 256), 256, 0, stream>>>(Wb + (size_t)i * 65536, WbT + (size_t)i * 65536, 256, 256);
    }
    k_transpose<<<cdiv((long)256 * 512, 256), 256, 0, stream>>>(Wd1, Wd1T, 256, 512);
    k_transpose<<<cdiv((long)512 * 1024, 256), 256, 0, stream>>>(Wd2, Wd2T, 512, 1024);

    // CSR (built once, reused for all 3 layers)
    k_zero_i32<<<cdiv(N, 256), 256, 0, stream>>>(deg, N);
    k_hist<<<cdiv(E, 256), 256, 0, stream>>>(e_dst, E, deg);
    int nb1 = cdiv(N, 1024);  // 49 (<= 64 required by k_scan2)
    k_scan1<<<nb1, 1024, 0, stream>>>(deg, rp, bsum, N);
    k_scan2<<<1, 64, 0, stream>>>(bsum, boff, nb1);
    k_scan3<<<cdiv(N, 256), 256, 0, stream>>>(rp, boff, cur, N, E);
    k_fill<<<cdiv(E, 256), 256, 0, stream>>>(e_src, e_dst, E, cur, esrc);

    const int ntM = cdiv(N, 256);  // 196

    // in_proj
    k_ln1024_in<<<N, 256, 0, stream>>>(x, ln_g, ln_b, xln);
    k_gemm256<1, 1, 0><<<ntM * 2, 512, 0, stream>>>(xln, W1T, b1, N, 1024, 512, h1, nullptr);
    k_gemm256<0, 1, 1><<<ntM * 1, 512, 0, stream>>>(h1, W2T, b2, N, 512, 256, hb, hf);

    // GNN blocks
    for (int i = 0; i < 3; i++) {
        k_agg<<<cdiv(N, 4), 256, 0, stream>>>(hf, hb, rp, esrc, zb16, N);
        k_gemm256<1, 1, 0><<<ntM * 1, 512, 0, stream>>>(zb16, WaT + (size_t)i * 65536, ba + (size_t)i * 256,
                                                        N, 256, 256, za, nullptr);
        k_gemm256<0, 0, 1><<<ntM * 1, 512, 0, stream>>>(za, WbT + (size_t)i * 65536, bb + (size_t)i * 256,
                                                        N, 256, 256, nullptr, zbf);
        k_ln256_relu_res<<<cdiv(N, 4), 256, 0, stream>>>(zbf, ng + (size_t)i * 256, nbt + (size_t)i * 256,
                                                         hf, hb, N);
    }

    // delta_proj + output LN
    k_gemm256<1, 1, 0><<<ntM * 2, 512, 0, stream>>>(hb, Wd1T, bd1, N, 256, 512, h1, nullptr);
    k_gemm256<0, 1, 0><<<ntM * 4, 512, 0, stream>>>(h1, Wd2T, bd2, N, 512, 1024, delta, nullptr);
    k_ln1024_out<<<N, 256, 0, stream>>>(x, delta, outg, outbeta, out);
}

// Round 5
// 1278.435 us; speedup vs baseline: 1.0121x; 1.0121x over previous
//
#include <hip/hip_runtime.h>
#include <hip/hip_bf16.h>

#define DEVI __device__ __forceinline__

using bf16x8 = __attribute__((ext_vector_type(8))) short;   // 8 bf16 in 4 VGPRs (per guide §3)
using f32x4  = __attribute__((ext_vector_type(4))) float;

DEVI unsigned short f2bf(float f) {
    unsigned u = __builtin_bit_cast(unsigned, f);
    return (unsigned short)((u + 0x7FFFu + ((u >> 16) & 1u)) >> 16);
}
DEVI float bf2f(unsigned short h) {
    return __builtin_bit_cast(float, (unsigned)h << 16);
}

DEVI f32x4 mfma16(bf16x8 a, bf16x8 b, f32x4 c) {
    return __builtin_amdgcn_mfma_f32_16x16x32_bf16(a, b, c, 0, 0, 0);
}

// async global->LDS, 16B per lane, LDS dest = wave-uniform base + lane*16 (guide §5)
DEVI void gl16(const void* g, void* l) {
    __builtin_amdgcn_global_load_lds((const __attribute__((address_space(1))) void*)g,
                                     (__attribute__((address_space(3))) void*)l,
                                     16, 0, 0);
}

// ---------------- weight transpose + bf16 cast: WT[n*K+k] = W[k*N+n] ----------------
__global__ void k_transpose(const float* __restrict__ W, unsigned short* __restrict__ WT,
                            int K, int N) {
    long i = (long)blockIdx.x * 256 + threadIdx.x;
    if (i >= (long)K * N) return;
    int nn = (int)(i / K);
    int kk = (int)(i - (long)nn * K);
    WT[i] = f2bf(W[(long)kk * N + nn]);
}

// ---------------- CSR build ----------------
__global__ void k_zero_i32(int* p, int n) {
    int i = blockIdx.x * 256 + threadIdx.x;
    if (i < n) p[i] = 0;
}
__global__ void k_hist(const int* __restrict__ dst, int E, int* __restrict__ deg) {
    int i = blockIdx.x * 256 + threadIdx.x;
    if (i < E) atomicAdd(&deg[dst[i]], 1);
}
__global__ __launch_bounds__(1024)
void k_scan1(const int* __restrict__ deg, int* __restrict__ rp, int* __restrict__ bsum, int n) {
    __shared__ int sh[1024];
    int t = threadIdx.x;
    int i = blockIdx.x * 1024 + t;
    int v = (i < n) ? deg[i] : 0;
    sh[t] = v;
    __syncthreads();
    for (int off = 1; off < 1024; off <<= 1) {
        int y = (t >= off) ? sh[t - off] : 0;
        __syncthreads();
        sh[t] += y;
        __syncthreads();
    }
    if (i < n) rp[i] = sh[t] - v;            // exclusive within block
    if (t == 1023) bsum[blockIdx.x] = sh[1023];
}
__global__ __launch_bounds__(64)
void k_scan2(const int* __restrict__ bsum, int* __restrict__ boff, int nb) {  // nb <= 64
    int lane = threadIdx.x;
    int v = (lane < nb) ? bsum[lane] : 0;
    int x = v;
    for (int off = 1; off < 64; off <<= 1) {
        int y = __shfl_up(x, off);
        if (lane >= off) x += y;
    }
    if (lane < nb) boff[lane] = x - v;
}
__global__ void k_scan3(int* __restrict__ rp, const int* __restrict__ boff,
                        int* __restrict__ cur, int n, int E) {
    int i = blockIdx.x * 256 + threadIdx.x;
    if (i < n) {
        int v = rp[i] + boff[i >> 10];
        rp[i] = v;
        cur[i] = v;
    }
    if (i == 0) rp[n] = E;
}
__global__ void k_fill(const int* __restrict__ src, const int* __restrict__ dst, int E,
                       int* __restrict__ cur, int* __restrict__ esrc) {
    int i = blockIdx.x * 256 + threadIdx.x;
    if (i < E) {
        int d = dst[i];
        int p = atomicAdd(&cur[d], 1);
        esrc[p] = src[i];
    }
}

// ---------------- LayerNorm kernels ----------------
__global__ __launch_bounds__(256)
void k_ln1024_in(const float* __restrict__ x, const float* __restrict__ g,
                 const float* __restrict__ b, unsigned short* __restrict__ out) {
    const long row = blockIdx.x;
    const int tid = threadIdx.x, lane = tid & 63, wid = tid >> 6;
    float4 v = ((const float4*)(x + row * 1024))[tid];
    float s = v.x + v.y + v.z + v.w;
    float s2 = v.x * v.x + v.y * v.y + v.z * v.z + v.w * v.w;
    for (int off = 1; off < 64; off <<= 1) { s += __shfl_xor(s, off); s2 += __shfl_xor(s2, off); }
    __shared__ float red[8];
    if (lane == 0) { red[wid] = s; red[4 + wid] = s2; }
    __syncthreads();
    s = red[0] + red[1] + red[2] + red[3];
    s2 = red[4] + red[5] + red[6] + red[7];
    float m = s * (1.f / 1024.f);
    float var = s2 * (1.f / 1024.f) - m * m;
    float inv = rsqrtf(var + 1e-5f);
    float4 gv = ((const float4*)g)[tid];
    float4 bv = ((const float4*)b)[tid];
    ushort4 o = make_ushort4(f2bf((v.x - m) * inv * gv.x + bv.x),
                             f2bf((v.y - m) * inv * gv.y + bv.y),
                             f2bf((v.z - m) * inv * gv.z + bv.z),
                             f2bf((v.w - m) * inv * gv.w + bv.w));
    ((ushort4*)(out + row * 1024))[tid] = o;
}

__global__ __launch_bounds__(256)
void k_ln1024_out(const float* __restrict__ x, const unsigned short* __restrict__ delta,
                  const float* __restrict__ g, const float* __restrict__ b,
                  float* __restrict__ out) {
    const long row = blockIdx.x;
    const int tid = threadIdx.x, lane = tid & 63, wid = tid >> 6;
    float4 xv = ((const float4*)(x + row * 1024))[tid];
    ushort4 dv = ((const ushort4*)(delta + row * 1024))[tid];
    float4 v;
    v.x = xv.x + bf2f(dv.x);
    v.y = xv.y + bf2f(dv.y);
    v.z = xv.z + bf2f(dv.z);
    v.w = xv.w + bf2f(dv.w);
    float s = v.x + v.y + v.z + v.w;
    float s2 = v.x * v.x + v.y * v.y + v.z * v.z + v.w * v.w;
    for (int off = 1; off < 64; off <<= 1) { s += __shfl_xor(s, off); s2 += __shfl_xor(s2, off); }
    __shared__ float red[8];
    if (lane == 0) { red[wid] = s; red[4 + wid] = s2; }
    __syncthreads();
    s = red[0] + red[1] + red[2] + red[3];
    s2 = red[4] + red[5] + red[6] + red[7];
    float m = s * (1.f / 1024.f);
    float var = s2 * (1.f / 1024.f) - m * m;
    float inv = rsqrtf(var + 1e-5f);
    float4 gv = ((const float4*)g)[tid];
    float4 bv = ((const float4*)b)[tid];
    float4 o;
    o.x = (v.x - m) * inv * gv.x + bv.x;
    o.y = (v.y - m) * inv * gv.y + bv.y;
    o.z = (v.z - m) * inv * gv.z + bv.z;
    o.w = (v.w - m) * inv * gv.w + bv.w;
    ((float4*)(out + row * 1024))[tid] = o;
}

// z-row LN -> ReLU -> residual add into h (fp32 master + bf16 shadow). One wave per row.
__global__ __launch_bounds__(256)
void k_ln256_relu_res(const float* __restrict__ z, const float* __restrict__ g,
                      const float* __restrict__ b, float* __restrict__ hf,
                      unsigned short* __restrict__ hb, int n) {
    int node = blockIdx.x * 4 + (threadIdx.x >> 6);
    if (node >= n) return;
    int lane = threadIdx.x & 63;
    long base = (long)node * 256;
    float4 v = ((const float4*)(z + base))[lane];
    float s = v.x + v.y + v.z + v.w;
    float s2 = v.x * v.x + v.y * v.y + v.z * v.z + v.w * v.w;
    for (int off = 1; off < 64; off <<= 1) { s += __shfl_xor(s, off); s2 += __shfl_xor(s2, off); }
    float m = s * (1.f / 256.f);
    float var = s2 * (1.f / 256.f) - m * m;
    float inv = rsqrtf(var + 1e-5f);
    float4 gv = ((const float4*)g)[lane];
    float4 bv = ((const float4*)b)[lane];
    float4 hv = ((const float4*)(hf + base))[lane];
    float4 o;
    o.x = hv.x + fmaxf((v.x - m) * inv * gv.x + bv.x, 0.f);
    o.y = hv.y + fmaxf((v.y - m) * inv * gv.y + bv.y, 0.f);
    o.z = hv.z + fmaxf((v.z - m) * inv * gv.z + bv.z, 0.f);
    o.w = hv.w + fmaxf((v.w - m) * inv * gv.w + bv.w, 0.f);
    ((float4*)(hf + base))[lane] = o;
    ushort4 ob = make_ushort4(f2bf(o.x), f2bf(o.y), f2bf(o.z), f2bf(o.w));
    ((ushort4*)(hb + base))[lane] = ob;
}

// ---------------- aggregation: z[dst] = h[dst] + sum_{src in-edges} h[src] ----------------
__global__ __launch_bounds__(256)
void k_agg(const float* __restrict__ hf, const unsigned short* __restrict__ hb,
           const int* __restrict__ rp, const int* __restrict__ esrc,
           unsigned short* __restrict__ z, int n) {
    int node = blockIdx.x * 4 + (threadIdx.x >> 6);
    if (node >= n) return;
    int lane = threadIdx.x & 63;
    float4 sv = ((const float4*)(hf + (long)node * 256))[lane];
    float a0 = sv.x, a1 = sv.y, a2 = sv.z, a3 = sv.w;
    int beg = rp[node], end = rp[node + 1];
    for (int e = beg; e < end; ++e) {
        int s = esrc[e];
        ushort4 hv = ((const ushort4*)(hb + (long)s * 256))[lane];
        a0 += bf2f(hv.x);
        a1 += bf2f(hv.y);
        a2 += bf2f(hv.z);
        a3 += bf2f(hv.w);
    }
    ushort4 o = make_ushort4(f2bf(a0), f2bf(a1), f2bf(a2), f2bf(a3));
    ((ushort4*)(z + (long)node * 256))[lane] = o;
}

// ---------------- bf16 MFMA GEMM: C[M,Nc] = act(A[M,K] @ W + bias), W given as WT[Nc,K] ----
// 128x128 tile, BK=32, 4 waves (2x2), each wave 64x64 via 4x4 mfma_16x16x32 fragments.
// Schedule = round-3 (proven): 3 LDS buffers, prefetch depth 2 (8 gl_lds in flight/wave),
// per K-step wait vmcnt(4) (drains ONLY the oldest tile's loads) + one barrier.
// LDS layout = round-4 (proven 0-conflict): subtile cells, cell(rg = 16-row group 0..7)
// holds [kg 0..3][fr 0..15][8 k] bf16; elem addr = rg*512 + kg*128 + fr*8.
//   - gl_lds writes cell linearly (lane l -> elems l*8, and l*8 == (l>>4)*128+(l&15)*8,
//     so lane l sources global row (rg*16 + l&15), k (l>>4)*8  — write/read permutations match.
//   - fragment ds_read_b128 at byte rg*1024 + kg0*256 + fr16*16: 16 lanes span all 32 banks,
//     2-way pairing only (free per m136). Kills round-3's 8-way row-stride-64B conflict.
template <int RELU, int WB, int WF>
__global__ __launch_bounds__(256)
void k_gemm(const unsigned short* __restrict__ A, const unsigned short* __restrict__ WT,
            const float* __restrict__ bias, int M, int K, int Nc,
            unsigned short* __restrict__ outb, float* __restrict__ outf) {
    __shared__ __align__(16) unsigned short lds_a[3 * 4096];
    __shared__ __align__(16) unsigned short lds_b[3 * 4096];
    const int tid = threadIdx.x;
    const int wid = tid >> 6, lane = tid & 63;
    const int fr16 = lane & 15, kg0 = lane >> 4;

    // bijective XCD swizzle (8 XCDs, round-robin dispatch; guide T1/m204)
    const int nwg = gridDim.x;
    const int q = nwg >> 3, r8 = nwg & 7;
    const int xcd = blockIdx.x & 7, sl = blockIdx.x >> 3;
    const int bid = (xcd < r8 ? xcd * (q + 1) : r8 * (q + 1) + (xcd - r8) * q) + sl;

    const int ntN = Nc >> 7;
    const int tM = bid / ntN, tN = bid - tM * ntN;
    const long row0 = (long)tM * 128;
    const int col0 = tN << 7;
    const int wr = wid >> 1, wc = wid & 1;

    // 4 staging issues per wave per K-step: j0,j1 = A cells rg {2w, 2w+1}; j2,j3 = B same.
    // per-lane global src: row = rg*16 + fr16, k-offset = kg0*8 (see layout comment).
    const unsigned short* gp[4];
    int lo[4];
#pragma unroll
    for (int j = 0; j < 4; ++j) {
        const int rg = 2 * wid + (j & 1);
        if (j < 2) {
            long rr = row0 + rg * 16 + fr16;
            if (rr > (long)M - 1) rr = M - 1;
            gp[j] = A + rr * K + kg0 * 8;
        } else {
            long rc = (long)col0 + rg * 16 + fr16;
            gp[j] = WT + rc * K + kg0 * 8;
        }
        lo[j] = rg * 512;   // wave-uniform LDS elem base of the cell (HW adds lane*16B)
    }

    f32x4 zero4 = {0.f, 0.f, 0.f, 0.f};
    f32x4 acc[4][4];
#pragma unroll
    for (int m = 0; m < 4; m++)
#pragma unroll
        for (int n = 0; n < 4; n++) acc[m][n] = zero4;

    const int laneRd = kg0 * 128 + fr16 * 8;   // per-lane elem offset within a cell

    auto STAGE = [&](int buf, int k0) {
        const int o = buf << 12;
        gl16(gp[0] + k0, &lds_a[o + lo[0]]);
        gl16(gp[1] + k0, &lds_a[o + lo[1]]);
        gl16(gp[2] + k0, &lds_b[o + lo[2]]);
        gl16(gp[3] + k0, &lds_b[o + lo[3]]);
    };
    auto COMPUTE = [&](int buf) {
        const int o = buf << 12;
        bf16x8 af[4], bfr[4];
#pragma unroll
        for (int m = 0; m < 4; m++) af[m] = *(const bf16x8*)&lds_a[o + (wr * 4 + m) * 512 + laneRd];
#pragma unroll
        for (int n = 0; n < 4; n++) bfr[n] = *(const bf16x8*)&lds_b[o + (wc * 4 + n) * 512 + laneRd];
#pragma unroll
        for (int m = 0; m < 4; m++)
#pragma unroll
            for (int n = 0; n < 4; n++) acc[m][n] = mfma16(af[m], bfr[n], acc[m][n]);
    };

    const int nsteps = K >> 5;          // K/32; all K here are multiples of 32, nsteps >= 8
    // prologue: tiles 0 and 1 in flight (8 outstanding gl_lds per wave)
    STAGE(0, 0);
    STAGE(1, 32);

    int bc = 0, bs = 2;                 // compute-buffer, stage-buffer (rotating mod 3)
    for (int s = 0; s < nsteps - 1; ++s) {
        asm volatile("s_waitcnt vmcnt(4)" ::: "memory");   // oldest tile landed; 4 stay in flight
        __builtin_amdgcn_s_barrier();
        const int k2 = (s + 2) << 5;
        if (k2 < K) STAGE(bs, k2);                         // skipped only at s == nsteps-2
        __builtin_amdgcn_sched_barrier(0);                 // pin: stage-issue before ds_reads
        COMPUTE(bc);
        bc = (bc == 2) ? 0 : bc + 1;
        bs = (bs == 2) ? 0 : bs + 1;
    }
    asm volatile("s_waitcnt vmcnt(0)" ::: "memory");       // drain last tile
    __builtin_amdgcn_s_barrier();
    COMPUTE(bc);

    // epilogue: per 16x16 frag D row = kg0*4 + r, col = fr16
#pragma unroll
    for (int n = 0; n < 4; n++) {
        int col = col0 + wc * 64 + n * 16 + fr16;
        float bv = bias[col];
#pragma unroll
        for (int m = 0; m < 4; m++) {
            long rb = row0 + wr * 64 + m * 16 + kg0 * 4;
#pragma unroll
            for (int r = 0; r < 4; r++) {
                long rr = rb + r;
                if (rr < M) {
                    float v = acc[m][n][r] + bv;
                    if (RELU) v = fmaxf(v, 0.f);
                    long idx = rr * Nc + col;
                    if (WB) outb[idx] = f2bf(v);
                    if (WF) outf[idx] = v;
                }
            }
        }
    }
}

// ---------------- host orchestration ----------------
extern "C" void kernel_launch(void* const* d_in, const int* in_sizes, int n_in,
                              void* d_out, int out_size, void* d_ws, size_t ws_size,
                              hipStream_t stream) {
    const float* x    = (const float*)d_in[0];
    const int*   eidx = (const int*)d_in[1];
    const float* ln_g = (const float*)d_in[2];
    const float* ln_b = (const float*)d_in[3];
    const float* W1   = (const float*)d_in[4];
    const float* b1   = (const float*)d_in[5];
    const float* W2   = (const float*)d_in[6];
    const float* b2   = (const float*)d_in[7];
    const float* Wa   = (const float*)d_in[8];
    const float* ba   = (const float*)d_in[9];
    const float* Wb   = (const float*)d_in[10];
    const float* bb   = (const float*)d_in[11];
    const float* ng   = (const float*)d_in[12];
    const float* nbt  = (const float*)d_in[13];
    const float* Wd1  = (const float*)d_in[14];
    const float* bd1  = (const float*)d_in[15];
    const float* Wd2  = (const float*)d_in[16];
    const float* bd2  = (const float*)d_in[17];
    const float* outg = (const float*)d_in[18];
    const float* outbeta = (const float*)d_in[19];
    float* out = (float*)d_out;

    const int N = in_sizes[0] / 1024;  // 50000
    const int E = in_sizes[1] / 2;     // 800000
    const int* e_src = eidx;
    const int* e_dst = eidx + E;

    char* ws = (char*)d_ws;
    size_t off = 0;
    auto alloc = [&](size_t bytes) -> char* {
        char* p = ws + off;
        off += (bytes + 255) & ~(size_t)255;
        return p;
    };

    // big multiplexed region: xln (N x 1024 bf16), later {z | za | zbf}, finally delta
    unsigned short* xln = (unsigned short*)alloc((size_t)N * 1024 * 2);
    unsigned short* zb16 = xln;                                          // N*256 bf16
    unsigned short* za   = (unsigned short*)((char*)xln + (size_t)N * 256 * 2);  // N*256 bf16
    float*          zbf  = (float*)((char*)xln + (size_t)N * 256 * 4);   // N*256 f32
    unsigned short* delta = xln;                                         // N*1024 bf16

    unsigned short* h1 = (unsigned short*)alloc((size_t)N * 512 * 2);    // also d1
    float*          hf = (float*)alloc((size_t)N * 256 * 4);
    unsigned short* hb = (unsigned short*)alloc((size_t)N * 256 * 2);

    unsigned short* W1T  = (unsigned short*)alloc((size_t)512 * 1024 * 2);
    unsigned short* W2T  = (unsigned short*)alloc((size_t)256 * 512 * 2);
    unsigned short* WaT  = (unsigned short*)alloc((size_t)3 * 256 * 256 * 2);
    unsigned short* WbT  = (unsigned short*)alloc((size_t)3 * 256 * 256 * 2);
    unsigned short* Wd1T = (unsigned short*)alloc((size_t)512 * 256 * 2);
    unsigned short* Wd2T = (unsigned short*)alloc((size_t)1024 * 512 * 2);

    int* deg  = (int*)alloc((size_t)(N + 1) * 4);
    int* rp   = (int*)alloc((size_t)(N + 1) * 4);
    int* cur  = (int*)alloc((size_t)N * 4);
    int* bsum = (int*)alloc(64 * 4);
    int* boff = (int*)alloc(64 * 4);
    int* esrc = (int*)alloc((size_t)E * 4);

    auto cdiv = [](long a, long b) { return (int)((a + b - 1) / b); };

    // weight prep
    k_transpose<<<cdiv((long)1024 * 512, 256), 256, 0, stream>>>(W1, W1T, 1024, 512);
    k_transpose<<<cdiv((long)512 * 256, 256), 256, 0, stream>>>(W2, W2T, 512, 256);
    for (int i = 0; i < 3; i++) {
        k_transpose<<<cdiv(65536, 256), 256, 0, stream>>>(Wa + (size_t)i * 65536, WaT + (size_t)i * 65536, 256, 256);
        k_transpose<<<cdiv(65536, 256), 256, 0, stream>>>(Wb + (size_t)i * 65536, WbT + (size_t)i * 65536, 256, 256);
    }
    k_transpose<<<cdiv((long)256 * 512, 256), 256, 0, stream>>>(Wd1, Wd1T, 256, 512);
    k_transpose<<<cdiv((long)512 * 1024, 256), 256, 0, stream>>>(Wd2, Wd2T, 512, 1024);

    // CSR (built once, reused for all 3 layers)
    k_zero_i32<<<cdiv(N, 256), 256, 0, stream>>>(deg, N);
    k_hist<<<cdiv(E, 256), 256, 0, stream>>>(e_dst, E, deg);
    int nb1 = cdiv(N, 1024);  // 49 (<= 64 required by k_scan2)
    k_scan1<<<nb1, 1024, 0, stream>>>(deg, rp, bsum, N);
    k_scan2<<<1, 64, 0, stream>>>(bsum, boff, nb1);
    k_scan3<<<cdiv(N, 256), 256, 0, stream>>>(rp, boff, cur, N, E);
    k_fill<<<cdiv(E, 256), 256, 0, stream>>>(e_src, e_dst, E, cur, esrc);

    const int ntM = cdiv(N, 128);  // 391

    // in_proj
    k_ln1024_in<<<N, 256, 0, stream>>>(x, ln_g, ln_b, xln);
    k_gemm<1, 1, 0><<<ntM * 4, 256, 0, stream>>>(xln, W1T, b1, N, 1024, 512, h1, nullptr);
    k_gemm<0, 1, 1><<<ntM * 2, 256, 0, stream>>>(h1, W2T, b2, N, 512, 256, hb, hf);

    // GNN blocks
    for (int i = 0; i < 3; i++) {
        k_agg<<<cdiv(N, 4), 256, 0, stream>>>(hf, hb, rp, esrc, zb16, N);
        k_gemm<1, 1, 0><<<ntM * 2, 256, 0, stream>>>(zb16, WaT + (size_t)i * 65536, ba + (size_t)i * 256,
                                                     N, 256, 256, za, nullptr);
        k_gemm<0, 0, 1><<<ntM * 2, 256, 0, stream>>>(za, WbT + (size_t)i * 65536, bb + (size_t)i * 256,
                                                     N, 256, 256, nullptr, zbf);
        k_ln256_relu_res<<<cdiv(N, 4), 256, 0, stream>>>(zbf, ng + (size_t)i * 256, nbt + (size_t)i * 256,
                                                         hf, hb, N);
    }

    // delta_proj + output LN
    k_gemm<1, 1, 0><<<ntM * 4, 256, 0, stream>>>(hb, Wd1T, bd1, N, 256, 512, h1, nullptr);
    k_gemm<0, 1, 0><<<ntM * 8, 256, 0, stream>>>(h1, Wd2T, bd2, N, 512, 1024, delta, nullptr);
    k_ln1024_out<<<N, 256, 0, stream>>>(x, delta, outg, outbeta, out);
}

// Round 6
// 1157.229 us; speedup vs baseline: 1.1181x; 1.1047x over previous
//
#include <hip/hip_runtime.h>
#include <hip/hip_bf16.h>

#define DEVI __device__ __forceinline__

using bf16x8 = __attribute__((ext_vector_type(8))) short;   // 8 bf16 in 4 VGPRs (per guide §3)
using f32x4  = __attribute__((ext_vector_type(4))) float;

DEVI unsigned short f2bf(float f) {
    unsigned u = __builtin_bit_cast(unsigned, f);
    return (unsigned short)((u + 0x7FFFu + ((u >> 16) & 1u)) >> 16);
}
DEVI float bf2f(unsigned short h) {
    return __builtin_bit_cast(float, (unsigned)h << 16);
}

DEVI f32x4 mfma16(bf16x8 a, bf16x8 b, f32x4 c) {
    return __builtin_amdgcn_mfma_f32_16x16x32_bf16(a, b, c, 0, 0, 0);
}

// async global->LDS, 16B per lane, LDS dest = wave-uniform base + lane*16 (guide §5)
DEVI void gl16(const void* g, void* l) {
    __builtin_amdgcn_global_load_lds((const __attribute__((address_space(1))) void*)g,
                                     (__attribute__((address_space(3))) void*)l,
                                     16, 0, 0);
}

// ---------------- weight transpose + bf16 cast: WT[n*K+k] = W[k*N+n] ----------------
__global__ void k_transpose(const float* __restrict__ W, unsigned short* __restrict__ WT,
                            int K, int N) {
    long i = (long)blockIdx.x * 256 + threadIdx.x;
    if (i >= (long)K * N) return;
    int nn = (int)(i / K);
    int kk = (int)(i - (long)nn * K);
    WT[i] = f2bf(W[(long)kk * N + nn]);
}

// ---------------- CSR build ----------------
__global__ void k_zero_i32(int* p, int n) {
    int i = blockIdx.x * 256 + threadIdx.x;
    if (i < n) p[i] = 0;
}
__global__ void k_hist(const int* __restrict__ dst, int E, int* __restrict__ deg) {
    int i = blockIdx.x * 256 + threadIdx.x;
    if (i < E) atomicAdd(&deg[dst[i]], 1);
}
__global__ __launch_bounds__(1024)
void k_scan1(const int* __restrict__ deg, int* __restrict__ rp, int* __restrict__ bsum, int n) {
    __shared__ int sh[1024];
    int t = threadIdx.x;
    int i = blockIdx.x * 1024 + t;
    int v = (i < n) ? deg[i] : 0;
    sh[t] = v;
    __syncthreads();
    for (int off = 1; off < 1024; off <<= 1) {
        int y = (t >= off) ? sh[t - off] : 0;
        __syncthreads();
        sh[t] += y;
        __syncthreads();
    }
    if (i < n) rp[i] = sh[t] - v;            // exclusive within block
    if (t == 1023) bsum[blockIdx.x] = sh[1023];
}
__global__ __launch_bounds__(64)
void k_scan2(const int* __restrict__ bsum, int* __restrict__ boff, int nb) {  // nb <= 64
    int lane = threadIdx.x;
    int v = (lane < nb) ? bsum[lane] : 0;
    int x = v;
    for (int off = 1; off < 64; off <<= 1) {
        int y = __shfl_up(x, off);
        if (lane >= off) x += y;
    }
    if (lane < nb) boff[lane] = x - v;
}
__global__ void k_scan3(int* __restrict__ rp, const int* __restrict__ boff,
                        int* __restrict__ cur, int n, int E) {
    int i = blockIdx.x * 256 + threadIdx.x;
    if (i < n) {
        int v = rp[i] + boff[i >> 10];
        rp[i] = v;
        cur[i] = v;
    }
    if (i == 0) rp[n] = E;
}
__global__ void k_fill(const int* __restrict__ src, const int* __restrict__ dst, int E,
                       int* __restrict__ cur, int* __restrict__ esrc) {
    int i = blockIdx.x * 256 + threadIdx.x;
    if (i < E) {
        int d = dst[i];
        int p = atomicAdd(&cur[d], 1);
        esrc[p] = src[i];
    }
}

// ---------------- LayerNorm kernels ----------------
__global__ __launch_bounds__(256)
void k_ln1024_in(const float* __restrict__ x, const float* __restrict__ g,
                 const float* __restrict__ b, unsigned short* __restrict__ out) {
    const long row = blockIdx.x;
    const int tid = threadIdx.x, lane = tid & 63, wid = tid >> 6;
    float4 v = ((const float4*)(x + row * 1024))[tid];
    float s = v.x + v.y + v.z + v.w;
    float s2 = v.x * v.x + v.y * v.y + v.z * v.z + v.w * v.w;
    for (int off = 1; off < 64; off <<= 1) { s += __shfl_xor(s, off); s2 += __shfl_xor(s2, off); }
    __shared__ float red[8];
    if (lane == 0) { red[wid] = s; red[4 + wid] = s2; }
    __syncthreads();
    s = red[0] + red[1] + red[2] + red[3];
    s2 = red[4] + red[5] + red[6] + red[7];
    float m = s * (1.f / 1024.f);
    float var = s2 * (1.f / 1024.f) - m * m;
    float inv = rsqrtf(var + 1e-5f);
    float4 gv = ((const float4*)g)[tid];
    float4 bv = ((const float4*)b)[tid];
    ushort4 o = make_ushort4(f2bf((v.x - m) * inv * gv.x + bv.x),
                             f2bf((v.y - m) * inv * gv.y + bv.y),
                             f2bf((v.z - m) * inv * gv.z + bv.z),
                             f2bf((v.w - m) * inv * gv.w + bv.w));
    ((ushort4*)(out + row * 1024))[tid] = o;
}

__global__ __launch_bounds__(256)
void k_ln1024_out(const float* __restrict__ x, const unsigned short* __restrict__ delta,
                  const float* __restrict__ g, const float* __restrict__ b,
                  float* __restrict__ out) {
    const long row = blockIdx.x;
    const int tid = threadIdx.x, lane = tid & 63, wid = tid >> 6;
    float4 xv = ((const float4*)(x + row * 1024))[tid];
    ushort4 dv = ((const ushort4*)(delta + row * 1024))[tid];
    float4 v;
    v.x = xv.x + bf2f(dv.x);
    v.y = xv.y + bf2f(dv.y);
    v.z = xv.z + bf2f(dv.z);
    v.w = xv.w + bf2f(dv.w);
    float s = v.x + v.y + v.z + v.w;
    float s2 = v.x * v.x + v.y * v.y + v.z * v.z + v.w * v.w;
    for (int off = 1; off < 64; off <<= 1) { s += __shfl_xor(s, off); s2 += __shfl_xor(s2, off); }
    __shared__ float red[8];
    if (lane == 0) { red[wid] = s; red[4 + wid] = s2; }
    __syncthreads();
    s = red[0] + red[1] + red[2] + red[3];
    s2 = red[4] + red[5] + red[6] + red[7];
    float m = s * (1.f / 1024.f);
    float var = s2 * (1.f / 1024.f) - m * m;
    float inv = rsqrtf(var + 1e-5f);
    float4 gv = ((const float4*)g)[tid];
    float4 bv = ((const float4*)b)[tid];
    float4 o;
    o.x = (v.x - m) * inv * gv.x + bv.x;
    o.y = (v.y - m) * inv * gv.y + bv.y;
    o.z = (v.z - m) * inv * gv.z + bv.z;
    o.w = (v.w - m) * inv * gv.w + bv.w;
    ((float4*)(out + row * 1024))[tid] = o;
}

// z-row LN -> ReLU -> residual add into h (fp32 master + bf16 shadow). One wave per row.
__global__ __launch_bounds__(256)
void k_ln256_relu_res(const float* __restrict__ z, const float* __restrict__ g,
                      const float* __restrict__ b, float* __restrict__ hf,
                      unsigned short* __restrict__ hb, int n) {
    int node = blockIdx.x * 4 + (threadIdx.x >> 6);
    if (node >= n) return;
    int lane = threadIdx.x & 63;
    long base = (long)node * 256;
    float4 v = ((const float4*)(z + base))[lane];
    float s = v.x + v.y + v.z + v.w;
    float s2 = v.x * v.x + v.y * v.y + v.z * v.z + v.w * v.w;
    for (int off = 1; off < 64; off <<= 1) { s += __shfl_xor(s, off); s2 += __shfl_xor(s2, off); }
    float m = s * (1.f / 256.f);
    float var = s2 * (1.f / 256.f) - m * m;
    float inv = rsqrtf(var + 1e-5f);
    float4 gv = ((const float4*)g)[lane];
    float4 bv = ((const float4*)b)[lane];
    float4 hv = ((const float4*)(hf + base))[lane];
    float4 o;
    o.x = hv.x + fmaxf((v.x - m) * inv * gv.x + bv.x, 0.f);
    o.y = hv.y + fmaxf((v.y - m) * inv * gv.y + bv.y, 0.f);
    o.z = hv.z + fmaxf((v.z - m) * inv * gv.z + bv.z, 0.f);
    o.w = hv.w + fmaxf((v.w - m) * inv * gv.w + bv.w, 0.f);
    ((float4*)(hf + base))[lane] = o;
    ushort4 ob = make_ushort4(f2bf(o.x), f2bf(o.y), f2bf(o.z), f2bf(o.w));
    ((ushort4*)(hb + base))[lane] = ob;
}

// ---------------- aggregation: z[dst] = h[dst] + sum_{src in-edges} h[src] ----------------
__global__ __launch_bounds__(256)
void k_agg(const float* __restrict__ hf, const unsigned short* __restrict__ hb,
           const int* __restrict__ rp, const int* __restrict__ esrc,
           unsigned short* __restrict__ z, int n) {
    int node = blockIdx.x * 4 + (threadIdx.x >> 6);
    if (node >= n) return;
    int lane = threadIdx.x & 63;
    float4 sv = ((const float4*)(hf + (long)node * 256))[lane];
    float a0 = sv.x, a1 = sv.y, a2 = sv.z, a3 = sv.w;
    int beg = rp[node], end = rp[node + 1];
    for (int e = beg; e < end; ++e) {
        int s = esrc[e];
        ushort4 hv = ((const ushort4*)(hb + (long)s * 256))[lane];
        a0 += bf2f(hv.x);
        a1 += bf2f(hv.y);
        a2 += bf2f(hv.z);
        a3 += bf2f(hv.w);
    }
    ushort4 o = make_ushort4(f2bf(a0), f2bf(a1), f2bf(a2), f2bf(a3));
    ((ushort4*)(z + (long)node * 256))[lane] = o;
}

// ---------------- bf16 MFMA GEMM: C[M,Nc] = act(A[M,K] @ W + bias), W given as WT[Nc,K] ----
// 128x128 tile, BK=32, 4 waves (2x2), each wave 64x64 via 4x4 mfma_16x16x32 fragments.
// Schedule = round-3 (proven best): 3 LDS buffers, prefetch depth 2 (8 gl_lds in flight),
// per K-step vmcnt(4) (drains ONLY the oldest tile) + one barrier.
// NEW: coalescing-preserving 16B-slot XOR swizzle. Rows stay row-major [row][32k] but the
// four 16B k-slots of each row are permuted: slot' = slot ^ ((row>>2)&3).
//   - write side (gl_lds is linear): lane 4f+kq of a staging op sources global
//     row0+16w+f, k-slot kq^((f>>2)&3). The quarter-wave still covers the row's full
//     contiguous 64B (reordered among its 4 lanes) -> coalescing identical to r3.
//   - read side: fragment byte = row*64 + (kg ^ ((row>>2)&3))*16. For each kg group of
//     16 lanes, slot values hit each s in {0..3} exactly twice per row-parity class ->
//     every bank serves exactly 2 lanes (free, m136). Kills r3's 8-way conflict.
template <int RELU, int WB, int WF>
__global__ __launch_bounds__(256)
void k_gemm(const unsigned short* __restrict__ A, const unsigned short* __restrict__ WT,
            const float* __restrict__ bias, int M, int K, int Nc,
            unsigned short* __restrict__ outb, float* __restrict__ outf) {
    __shared__ __align__(16) unsigned short lds_a[3 * 4096];
    __shared__ __align__(16) unsigned short lds_b[3 * 4096];
    const int tid = threadIdx.x;
    const int wid = tid >> 6, lane = tid & 63;

    // bijective XCD swizzle (8 XCDs, round-robin dispatch; guide T1/m204)
    const int nwg = gridDim.x;
    const int q = nwg >> 3, r8 = nwg & 7;
    const int xcd = blockIdx.x & 7, sl = blockIdx.x >> 3;
    const int bid = (xcd < r8 ? xcd * (q + 1) : r8 * (q + 1) + (xcd - r8) * q) + sl;

    const int ntN = Nc >> 7;
    const int tM = bid / ntN, tN = bid - tM * ntN;
    const long row0 = (long)tM * 128;
    const int col0 = tN << 7;
    const int wr = wid >> 1, wc = wid & 1;

    // staging: thread t covers row sr=t>>2 (per 64-row half), k-slot (t&3)^((sr>>2)&3).
    // LDS write stays linear (HW: wave base + lane*16B) == row-major [sr&15][slot 0..3].
    const int sr = tid >> 2;
    const int sc = (((tid & 3) ^ ((sr >> 2) & 3)) << 3);   // elems (8 elems = 16B slot)
    long ra0 = row0 + sr;       if (ra0 > (long)M - 1) ra0 = M - 1;
    long ra1 = row0 + sr + 64;  if (ra1 > (long)M - 1) ra1 = M - 1;
    const unsigned short* pa0 = A + ra0 * K + sc;
    const unsigned short* pa1 = A + ra1 * K + sc;
    const unsigned short* pb0 = WT + (long)(col0 + sr) * K + sc;
    const unsigned short* pb1 = WT + (long)(col0 + sr + 64) * K + sc;

    f32x4 zero4 = {0.f, 0.f, 0.f, 0.f};
    f32x4 acc[4][4];
#pragma unroll
    for (int m = 0; m < 4; m++)
#pragma unroll
        for (int n = 0; n < 4; n++) acc[m][n] = zero4;

    // fragment read: row fr, k-group kg -> swizzled slot s4 = kg ^ ((fr>>2)&3)
    const int fr = lane & 15, kg = lane >> 4;
    const int s4 = kg ^ ((fr >> 2) & 3);
    const unsigned short* la = &lds_a[(wr * 64 + fr) * 32 + s4 * 8];
    const unsigned short* lb = &lds_b[(wc * 64 + fr) * 32 + s4 * 8];

    // buf b occupies elems [b*4096, b*4096+4096) of each LDS array
    auto STAGE = [&](int buf, int k0) {
        const int o = buf << 12;
        gl16(pa0 + k0, &lds_a[o + wid * 512]);
        gl16(pa1 + k0, &lds_a[o + 2048 + wid * 512]);
        gl16(pb0 + k0, &lds_b[o + wid * 512]);
        gl16(pb1 + k0, &lds_b[o + 2048 + wid * 512]);
    };
    auto COMPUTE = [&](int buf) {
        const int o = buf << 12;
        bf16x8 af[4], bfr[4];
#pragma unroll
        for (int m = 0; m < 4; m++) af[m] = *(const bf16x8*)(la + o + m * 16 * 32);
#pragma unroll
        for (int n = 0; n < 4; n++) bfr[n] = *(const bf16x8*)(lb + o + n * 16 * 32);
#pragma unroll
        for (int m = 0; m < 4; m++)
#pragma unroll
            for (int n = 0; n < 4; n++) acc[m][n] = mfma16(af[m], bfr[n], acc[m][n]);
    };

    const int nsteps = K >> 5;          // K/32; all K here are multiples of 32, nsteps >= 8
    // prologue: tiles 0 and 1 in flight (8 outstanding gl_lds per wave)
    STAGE(0, 0);
    STAGE(1, 32);

    int bc = 0, bs = 2;                 // compute-buffer, stage-buffer (rotating mod 3)
    for (int s = 0; s < nsteps - 1; ++s) {
        asm volatile("s_waitcnt vmcnt(4)" ::: "memory");   // oldest tile landed; 4 stay in flight
        __builtin_amdgcn_s_barrier();
        const int k2 = (s + 2) << 5;
        if (k2 < K) STAGE(bs, k2);                         // skipped only at s == nsteps-2
        __builtin_amdgcn_sched_barrier(0);                 // pin: stage-issue before ds_reads
        COMPUTE(bc);
        bc = (bc == 2) ? 0 : bc + 1;
        bs = (bs == 2) ? 0 : bs + 1;
    }
    asm volatile("s_waitcnt vmcnt(0)" ::: "memory");       // drain last tile
    __builtin_amdgcn_s_barrier();
    COMPUTE(bc);

    // epilogue: per 16x16 frag D row = kg*4 + r, col = fr
#pragma unroll
    for (int n = 0; n < 4; n++) {
        int col = col0 + wc * 64 + n * 16 + fr;
        float bv = bias[col];
#pragma unroll
        for (int m = 0; m < 4; m++) {
            long rb = row0 + wr * 64 + m * 16 + kg * 4;
#pragma unroll
            for (int r = 0; r < 4; r++) {
                long rr = rb + r;
                if (rr < M) {
                    float v = acc[m][n][r] + bv;
                    if (RELU) v = fmaxf(v, 0.f);
                    long idx = rr * Nc + col;
                    if (WB) outb[idx] = f2bf(v);
                    if (WF) outf[idx] = v;
                }
            }
        }
    }
}

// ---------------- host orchestration ----------------
extern "C" void kernel_launch(void* const* d_in, const int* in_sizes, int n_in,
                              void* d_out, int out_size, void* d_ws, size_t ws_size,
                              hipStream_t stream) {
    const float* x    = (const float*)d_in[0];
    const int*   eidx = (const int*)d_in[1];
    const float* ln_g = (const float*)d_in[2];
    const float* ln_b = (const float*)d_in[3];
    const float* W1   = (const float*)d_in[4];
    const float* b1   = (const float*)d_in[5];
    const float* W2   = (const float*)d_in[6];
    const float* b2   = (const float*)d_in[7];
    const float* Wa   = (const float*)d_in[8];
    const float* ba   = (const float*)d_in[9];
    const float* Wb   = (const float*)d_in[10];
    const float* bb   = (const float*)d_in[11];
    const float* ng   = (const float*)d_in[12];
    const float* nbt  = (const float*)d_in[13];
    const float* Wd1  = (const float*)d_in[14];
    const float* bd1  = (const float*)d_in[15];
    const float* Wd2  = (const float*)d_in[16];
    const float* bd2  = (const float*)d_in[17];
    const float* outg = (const float*)d_in[18];
    const float* outbeta = (const float*)d_in[19];
    float* out = (float*)d_out;

    const int N = in_sizes[0] / 1024;  // 50000
    const int E = in_sizes[1] / 2;     // 800000
    const int* e_src = eidx;
    const int* e_dst = eidx + E;

    char* ws = (char*)d_ws;
    size_t off = 0;
    auto alloc = [&](size_t bytes) -> char* {
        char* p = ws + off;
        off += (bytes + 255) & ~(size_t)255;
        return p;
    };

    // big multiplexed region: xln (N x 1024 bf16), later {z | za | zbf}, finally delta
    unsigned short* xln = (unsigned short*)alloc((size_t)N * 1024 * 2);
    unsigned short* zb16 = xln;                                          // N*256 bf16
    unsigned short* za   = (unsigned short*)((char*)xln + (size_t)N * 256 * 2);  // N*256 bf16
    float*          zbf  = (float*)((char*)xln + (size_t)N * 256 * 4);   // N*256 f32
    unsigned short* delta = xln;                                         // N*1024 bf16

    unsigned short* h1 = (unsigned short*)alloc((size_t)N * 512 * 2);    // also d1
    float*          hf = (float*)alloc((size_t)N * 256 * 4);
    unsigned short* hb = (unsigned short*)alloc((size_t)N * 256 * 2);

    unsigned short* W1T  = (unsigned short*)alloc((size_t)512 * 1024 * 2);
    unsigned short* W2T  = (unsigned short*)alloc((size_t)256 * 512 * 2);
    unsigned short* WaT  = (unsigned short*)alloc((size_t)3 * 256 * 256 * 2);
    unsigned short* WbT  = (unsigned short*)alloc((size_t)3 * 256 * 256 * 2);
    unsigned short* Wd1T = (unsigned short*)alloc((size_t)512 * 256 * 2);
    unsigned short* Wd2T = (unsigned short*)alloc((size_t)1024 * 512 * 2);

    int* deg  = (int*)alloc((size_t)(N + 1) * 4);
    int* rp   = (int*)alloc((size_t)(N + 1) * 4);
    int* cur  = (int*)alloc((size_t)N * 4);
    int* bsum = (int*)alloc(64 * 4);
    int* boff = (int*)alloc(64 * 4);
    int* esrc = (int*)alloc((size_t)E * 4);

    auto cdiv = [](long a, long b) { return (int)((a + b - 1) / b); };

    // weight prep
    k_transpose<<<cdiv((long)1024 * 512, 256), 256, 0, stream>>>(W1, W1T, 1024, 512);
    k_transpose<<<cdiv((long)512 * 256, 256), 256, 0, stream>>>(W2, W2T, 512, 256);
    for (int i = 0; i < 3; i++) {
        k_transpose<<<cdiv(65536, 256), 256, 0, stream>>>(Wa + (size_t)i * 65536, WaT + (size_t)i * 65536, 256, 256);
        k_transpose<<<cdiv(65536, 256), 256, 0, stream>>>(Wb + (size_t)i * 65536, WbT + (size_t)i * 65536, 256, 256);
    }
    k_transpose<<<cdiv((long)256 * 512, 256), 256, 0, stream>>>(Wd1, Wd1T, 256, 512);
    k_transpose<<<cdiv((long)512 * 1024, 256), 256, 0, stream>>>(Wd2, Wd2T, 512, 1024);

    // CSR (built once, reused for all 3 layers)
    k_zero_i32<<<cdiv(N, 256), 256, 0, stream>>>(deg, N);
    k_hist<<<cdiv(E, 256), 256, 0, stream>>>(e_dst, E, deg);
    int nb1 = cdiv(N, 1024);  // 49 (<= 64 required by k_scan2)
    k_scan1<<<nb1, 1024, 0, stream>>>(deg, rp, bsum, N);
    k_scan2<<<1, 64, 0, stream>>>(bsum, boff, nb1);
    k_scan3<<<cdiv(N, 256), 256, 0, stream>>>(rp, boff, cur, N, E);
    k_fill<<<cdiv(E, 256), 256, 0, stream>>>(e_src, e_dst, E, cur, esrc);

    const int ntM = cdiv(N, 128);  // 391

    // in_proj
    k_ln1024_in<<<N, 256, 0, stream>>>(x, ln_g, ln_b, xln);
    k_gemm<1, 1, 0><<<ntM * 4, 256, 0, stream>>>(xln, W1T, b1, N, 1024, 512, h1, nullptr);
    k_gemm<0, 1, 1><<<ntM * 2, 256, 0, stream>>>(h1, W2T, b2, N, 512, 256, hb, hf);

    // GNN blocks
    for (int i = 0; i < 3; i++) {
        k_agg<<<cdiv(N, 4), 256, 0, stream>>>(hf, hb, rp, esrc, zb16, N);
        k_gemm<1, 1, 0><<<ntM * 2, 256, 0, stream>>>(zb16, WaT + (size_t)i * 65536, ba + (size_t)i * 256,
                                                     N, 256, 256, za, nullptr);
        k_gemm<0, 0, 1><<<ntM * 2, 256, 0, stream>>>(za, WbT + (size_t)i * 65536, bb + (size_t)i * 256,
                                                     N, 256, 256, nullptr, zbf);
        k_ln256_relu_res<<<cdiv(N, 4), 256, 0, stream>>>(zbf, ng + (size_t)i * 256, nbt + (size_t)i * 256,
                                                         hf, hb, N);
    }

    // delta_proj + output LN
    k_gemm<1, 1, 0><<<ntM * 4, 256, 0, stream>>>(hb, Wd1T, bd1, N, 256, 512, h1, nullptr);
    k_gemm<0, 1, 0><<<ntM * 8, 256, 0, stream>>>(h1, Wd2T, bd2, N, 512, 1024, delta, nullptr);
    k_ln1024_out<<<N, 256, 0, stream>>>(x, delta, outg, outbeta, out);
}

// Round 7
// 1098.134 us; speedup vs baseline: 1.1783x; 1.0538x over previous
//
#include <hip/hip_runtime.h>
#include <hip/hip_bf16.h>

#define DEVI __device__ __forceinline__

using bf16x8 = __attribute__((ext_vector_type(8))) short;   // 8 bf16 in 4 VGPRs (per guide §3)
using f32x4  = __attribute__((ext_vector_type(4))) float;

DEVI unsigned short f2bf(float f) {
    unsigned u = __builtin_bit_cast(unsigned, f);
    return (unsigned short)((u + 0x7FFFu + ((u >> 16) & 1u)) >> 16);
}
DEVI float bf2f(unsigned short h) {
    return __builtin_bit_cast(float, (unsigned)h << 16);
}

DEVI f32x4 mfma16(bf16x8 a, bf16x8 b, f32x4 c) {
    return __builtin_amdgcn_mfma_f32_16x16x32_bf16(a, b, c, 0, 0, 0);
}

// async global->LDS, 16B per lane, LDS dest = wave-uniform base + lane*16 (guide §5)
DEVI void gl16(const void* g, void* l) {
    __builtin_amdgcn_global_load_lds((const __attribute__((address_space(1))) void*)g,
                                     (__attribute__((address_space(3))) void*)l,
                                     16, 0, 0);
}

// ---------------- weight transpose + bf16 cast: WT[n*K+k] = W[k*N+n] ----------------
__global__ void k_transpose(const float* __restrict__ W, unsigned short* __restrict__ WT,
                            int K, int N) {
    long i = (long)blockIdx.x * 256 + threadIdx.x;
    if (i >= (long)K * N) return;
    int nn = (int)(i / K);
    int kk = (int)(i - (long)nn * K);
    WT[i] = f2bf(W[(long)kk * N + nn]);
}

// ---------------- CSR build ----------------
__global__ void k_zero_i32(int* p, int n) {
    int i = blockIdx.x * 256 + threadIdx.x;
    if (i < n) p[i] = 0;
}
__global__ void k_hist(const int* __restrict__ dst, int E, int* __restrict__ deg) {
    int i = blockIdx.x * 256 + threadIdx.x;
    if (i < E) atomicAdd(&deg[dst[i]], 1);
}
__global__ __launch_bounds__(1024)
void k_scan1(const int* __restrict__ deg, int* __restrict__ rp, int* __restrict__ bsum, int n) {
    __shared__ int sh[1024];
    int t = threadIdx.x;
    int i = blockIdx.x * 1024 + t;
    int v = (i < n) ? deg[i] : 0;
    sh[t] = v;
    __syncthreads();
    for (int off = 1; off < 1024; off <<= 1) {
        int y = (t >= off) ? sh[t - off] : 0;
        __syncthreads();
        sh[t] += y;
        __syncthreads();
    }
    if (i < n) rp[i] = sh[t] - v;            // exclusive within block
    if (t == 1023) bsum[blockIdx.x] = sh[1023];
}
__global__ __launch_bounds__(64)
void k_scan2(const int* __restrict__ bsum, int* __restrict__ boff, int nb) {  // nb <= 64
    int lane = threadIdx.x;
    int v = (lane < nb) ? bsum[lane] : 0;
    int x = v;
    for (int off = 1; off < 64; off <<= 1) {
        int y = __shfl_up(x, off);
        if (lane >= off) x += y;
    }
    if (lane < nb) boff[lane] = x - v;
}
__global__ void k_scan3(int* __restrict__ rp, const int* __restrict__ boff,
                        int* __restrict__ cur, int n, int E) {
    int i = blockIdx.x * 256 + threadIdx.x;
    if (i < n) {
        int v = rp[i] + boff[i >> 10];
        rp[i] = v;
        cur[i] = v;
    }
    if (i == 0) rp[n] = E;
}
__global__ void k_fill(const int* __restrict__ src, const int* __restrict__ dst, int E,
                       int* __restrict__ cur, int* __restrict__ esrc) {
    int i = blockIdx.x * 256 + threadIdx.x;
    if (i < E) {
        int d = dst[i];
        int p = atomicAdd(&cur[d], 1);
        esrc[p] = src[i];
    }
}

// ---------------- LayerNorm kernels ----------------
__global__ __launch_bounds__(256)
void k_ln1024_in(const float* __restrict__ x, const float* __restrict__ g,
                 const float* __restrict__ b, unsigned short* __restrict__ out) {
    const long row = blockIdx.x;
    const int tid = threadIdx.x, lane = tid & 63, wid = tid >> 6;
    float4 v = ((const float4*)(x + row * 1024))[tid];
    float s = v.x + v.y + v.z + v.w;
    float s2 = v.x * v.x + v.y * v.y + v.z * v.z + v.w * v.w;
    for (int off = 1; off < 64; off <<= 1) { s += __shfl_xor(s, off); s2 += __shfl_xor(s2, off); }
    __shared__ float red[8];
    if (lane == 0) { red[wid] = s; red[4 + wid] = s2; }
    __syncthreads();
    s = red[0] + red[1] + red[2] + red[3];
    s2 = red[4] + red[5] + red[6] + red[7];
    float m = s * (1.f / 1024.f);
    float var = s2 * (1.f / 1024.f) - m * m;
    float inv = rsqrtf(var + 1e-5f);
    float4 gv = ((const float4*)g)[tid];
    float4 bv = ((const float4*)b)[tid];
    ushort4 o = make_ushort4(f2bf((v.x - m) * inv * gv.x + bv.x),
                             f2bf((v.y - m) * inv * gv.y + bv.y),
                             f2bf((v.z - m) * inv * gv.z + bv.z),
                             f2bf((v.w - m) * inv * gv.w + bv.w));
    ((ushort4*)(out + row * 1024))[tid] = o;
}

__global__ __launch_bounds__(256)
void k_ln1024_out(const float* __restrict__ x, const unsigned short* __restrict__ delta,
                  const float* __restrict__ g, const float* __restrict__ b,
                  float* __restrict__ out) {
    const long row = blockIdx.x;
    const int tid = threadIdx.x, lane = tid & 63, wid = tid >> 6;
    float4 xv = ((const float4*)(x + row * 1024))[tid];
    ushort4 dv = ((const ushort4*)(delta + row * 1024))[tid];
    float4 v;
    v.x = xv.x + bf2f(dv.x);
    v.y = xv.y + bf2f(dv.y);
    v.z = xv.z + bf2f(dv.z);
    v.w = xv.w + bf2f(dv.w);
    float s = v.x + v.y + v.z + v.w;
    float s2 = v.x * v.x + v.y * v.y + v.z * v.z + v.w * v.w;
    for (int off = 1; off < 64; off <<= 1) { s += __shfl_xor(s, off); s2 += __shfl_xor(s2, off); }
    __shared__ float red[8];
    if (lane == 0) { red[wid] = s; red[4 + wid] = s2; }
    __syncthreads();
    s = red[0] + red[1] + red[2] + red[3];
    s2 = red[4] + red[5] + red[6] + red[7];
    float m = s * (1.f / 1024.f);
    float var = s2 * (1.f / 1024.f) - m * m;
    float inv = rsqrtf(var + 1e-5f);
    float4 gv = ((const float4*)g)[tid];
    float4 bv = ((const float4*)b)[tid];
    float4 o;
    o.x = (v.x - m) * inv * gv.x + bv.x;
    o.y = (v.y - m) * inv * gv.y + bv.y;
    o.z = (v.z - m) * inv * gv.z + bv.z;
    o.w = (v.w - m) * inv * gv.w + bv.w;
    ((float4*)(out + row * 1024))[tid] = o;
}

// ---------------- aggregation: z[dst] = h[dst] + sum_{src in-edges} h[src] ----------------
__global__ __launch_bounds__(256)
void k_agg(const float* __restrict__ hf, const unsigned short* __restrict__ hb,
           const int* __restrict__ rp, const int* __restrict__ esrc,
           unsigned short* __restrict__ z, int n) {
    int node = blockIdx.x * 4 + (threadIdx.x >> 6);
    if (node >= n) return;
    int lane = threadIdx.x & 63;
    float4 sv = ((const float4*)(hf + (long)node * 256))[lane];
    float a0 = sv.x, a1 = sv.y, a2 = sv.z, a3 = sv.w;
    int beg = rp[node], end = rp[node + 1];
    for (int e = beg; e < end; ++e) {
        int s = esrc[e];
        ushort4 hv = ((const ushort4*)(hb + (long)s * 256))[lane];
        a0 += bf2f(hv.x);
        a1 += bf2f(hv.y);
        a2 += bf2f(hv.z);
        a3 += bf2f(hv.w);
    }
    ushort4 o = make_ushort4(f2bf(a0), f2bf(a1), f2bf(a2), f2bf(a3));
    ((ushort4*)(z + (long)node * 256))[lane] = o;
}

// ---------------- bf16 MFMA GEMM: C[M,Nc] = act(A[M,K] @ W + bias), W given as WT[Nc,K] ----
// 128x128 tile, BK=32, 4 waves (2x2). Proven r3 schedule: 3 LDS buffers, depth-2 prefetch,
// per K-step vmcnt(4) + one barrier. (Slot swizzle from r6 kept: timing-neutral.)
template <int RELU, int WB, int WF>
__global__ __launch_bounds__(256)
void k_gemm(const unsigned short* __restrict__ A, const unsigned short* __restrict__ WT,
            const float* __restrict__ bias, int M, int K, int Nc,
            unsigned short* __restrict__ outb, float* __restrict__ outf) {
    __shared__ __align__(16) unsigned short lds_a[3 * 4096];
    __shared__ __align__(16) unsigned short lds_b[3 * 4096];
    const int tid = threadIdx.x;
    const int wid = tid >> 6, lane = tid & 63;

    // bijective XCD swizzle (8 XCDs, round-robin dispatch; guide T1/m204)
    const int nwg = gridDim.x;
    const int q = nwg >> 3, r8 = nwg & 7;
    const int xcd = blockIdx.x & 7, sl = blockIdx.x >> 3;
    const int bid = (xcd < r8 ? xcd * (q + 1) : r8 * (q + 1) + (xcd - r8) * q) + sl;

    const int ntN = Nc >> 7;
    const int tM = bid / ntN, tN = bid - tM * ntN;
    const long row0 = (long)tM * 128;
    const int col0 = tN << 7;
    const int wr = wid >> 1, wc = wid & 1;

    const int sr = tid >> 2;
    const int sc = (((tid & 3) ^ ((sr >> 2) & 3)) << 3);
    long ra0 = row0 + sr;       if (ra0 > (long)M - 1) ra0 = M - 1;
    long ra1 = row0 + sr + 64;  if (ra1 > (long)M - 1) ra1 = M - 1;
    const unsigned short* pa0 = A + ra0 * K + sc;
    const unsigned short* pa1 = A + ra1 * K + sc;
    const unsigned short* pb0 = WT + (long)(col0 + sr) * K + sc;
    const unsigned short* pb1 = WT + (long)(col0 + sr + 64) * K + sc;

    f32x4 zero4 = {0.f, 0.f, 0.f, 0.f};
    f32x4 acc[4][4];
#pragma unroll
    for (int m = 0; m < 4; m++)
#pragma unroll
        for (int n = 0; n < 4; n++) acc[m][n] = zero4;

    const int fr = lane & 15, kg = lane >> 4;
    const int s4 = kg ^ ((fr >> 2) & 3);
    const unsigned short* la = &lds_a[(wr * 64 + fr) * 32 + s4 * 8];
    const unsigned short* lb = &lds_b[(wc * 64 + fr) * 32 + s4 * 8];

    auto STAGE = [&](int buf, int k0) {
        const int o = buf << 12;
        gl16(pa0 + k0, &lds_a[o + wid * 512]);
        gl16(pa1 + k0, &lds_a[o + 2048 + wid * 512]);
        gl16(pb0 + k0, &lds_b[o + wid * 512]);
        gl16(pb1 + k0, &lds_b[o + 2048 + wid * 512]);
    };
    auto COMPUTE = [&](int buf) {
        const int o = buf << 12;
        bf16x8 af[4], bfr[4];
#pragma unroll
        for (int m = 0; m < 4; m++) af[m] = *(const bf16x8*)(la + o + m * 16 * 32);
#pragma unroll
        for (int n = 0; n < 4; n++) bfr[n] = *(const bf16x8*)(lb + o + n * 16 * 32);
#pragma unroll
        for (int m = 0; m < 4; m++)
#pragma unroll
            for (int n = 0; n < 4; n++) acc[m][n] = mfma16(af[m], bfr[n], acc[m][n]);
    };

    const int nsteps = K >> 5;
    STAGE(0, 0);
    STAGE(1, 32);

    int bc = 0, bs = 2;
    for (int s = 0; s < nsteps - 1; ++s) {
        asm volatile("s_waitcnt vmcnt(4)" ::: "memory");
        __builtin_amdgcn_s_barrier();
        const int k2 = (s + 2) << 5;
        if (k2 < K) STAGE(bs, k2);
        __builtin_amdgcn_sched_barrier(0);
        COMPUTE(bc);
        bc = (bc == 2) ? 0 : bc + 1;
        bs = (bs == 2) ? 0 : bs + 1;
    }
    asm volatile("s_waitcnt vmcnt(0)" ::: "memory");
    __builtin_amdgcn_s_barrier();
    COMPUTE(bc);

#pragma unroll
    for (int n = 0; n < 4; n++) {
        int col = col0 + wc * 64 + n * 16 + fr;
        float bv = bias[col];
#pragma unroll
        for (int m = 0; m < 4; m++) {
            long rb = row0 + wr * 64 + m * 16 + kg * 4;
#pragma unroll
            for (int r = 0; r < 4; r++) {
                long rr = rb + r;
                if (rr < M) {
                    float v = acc[m][n][r] + bv;
                    if (RELU) v = fmaxf(v, 0.f);
                    long idx = rr * Nc + col;
                    if (WB) outb[idx] = f2bf(v);
                    if (WF) outf[idx] = v;
                }
            }
        }
    }
}

// ---------------- fused layer-B GEMM + LayerNorm(256) + ReLU + residual ----------------
// C = za @ Wb + bb  -> z = relu(LN(C)) -> hf += z (fp32), hb = bf16(hf).
// BM=128, BN=256=Nc (block owns FULL rows -> row-LN in epilogue), K=256 fixed.
// 8 waves (2Mx4N), per-wave 64x64 tile, acc 4x4 -- same per-wave structure & schedule as
// k_gemm (3 bufs, depth-2, counted vmcnt; 3 gl_lds/wave/step -> vmcnt(3)).
__global__ __launch_bounds__(512)
void k_gemm_fused_ln(const unsigned short* __restrict__ A, const unsigned short* __restrict__ WT,
                     const float* __restrict__ bias, const float* __restrict__ g,
                     const float* __restrict__ b, float* __restrict__ hf,
                     unsigned short* __restrict__ hb, int M) {
    __shared__ __align__(16) unsigned short lds_a[3 * 4096];   // 3 x [128][32]
    __shared__ __align__(16) unsigned short lds_b[3 * 8192];   // 3 x [256][32]
    __shared__ float red_s[128][4];
    __shared__ float red_q[128][4];
    const int tid = threadIdx.x, wid = tid >> 6, lane = tid & 63;
    const int fr = lane & 15, kg = lane >> 4;

    // bijective XCD swizzle
    const int nwg = gridDim.x;
    const int q = nwg >> 3, r8 = nwg & 7;
    const int xcd = blockIdx.x & 7, sl = blockIdx.x >> 3;
    const int bid = (xcd < r8 ? xcd * (q + 1) : r8 * (q + 1) + (xcd - r8) * q) + sl;
    const long row0 = (long)bid * 128;
    const int wr = wid >> 2, wn = wid & 3;

    // staging sources: wave wid stages A rows [wid*16,+16), WT rows [wid*16,+16) and [128+wid*16,+16)
    // lane l -> row l>>2 of the 16, 16B slot l&3 (linear LDS write == row-major [16][32])
    const int srow = lane >> 2, slot = lane & 3;
    long ar = row0 + wid * 16 + srow; if (ar > (long)M - 1) ar = M - 1;
    const unsigned short* pa  = A + ar * 256 + slot * 8;
    const unsigned short* pb0 = WT + (long)(wid * 16 + srow) * 256 + slot * 8;
    const unsigned short* pb1 = WT + (long)(128 + wid * 16 + srow) * 256 + slot * 8;

    f32x4 zero4 = {0.f, 0.f, 0.f, 0.f};
    f32x4 acc[4][4];
#pragma unroll
    for (int m = 0; m < 4; m++)
#pragma unroll
        for (int n = 0; n < 4; n++) acc[m][n] = zero4;

    auto STAGE = [&](int buf, int k0) {
        gl16(pa + k0, &lds_a[buf * 4096 + wid * 512]);
        gl16(pb0 + k0, &lds_b[buf * 8192 + wid * 512]);
        gl16(pb1 + k0, &lds_b[buf * 8192 + 4096 + wid * 512]);
    };
    auto COMPUTE = [&](int buf) {
        bf16x8 af[4], bfr[4];
#pragma unroll
        for (int m = 0; m < 4; m++)
            af[m] = *(const bf16x8*)&lds_a[buf * 4096 + (wr * 64 + m * 16 + fr) * 32 + kg * 8];
#pragma unroll
        for (int n = 0; n < 4; n++)
            bfr[n] = *(const bf16x8*)&lds_b[buf * 8192 + (wn * 64 + n * 16 + fr) * 32 + kg * 8];
#pragma unroll
        for (int m = 0; m < 4; m++)
#pragma unroll
            for (int n = 0; n < 4; n++) acc[m][n] = mfma16(af[m], bfr[n], acc[m][n]);
    };

    // K=256 -> 8 steps
    STAGE(0, 0);
    STAGE(1, 32);
    int bc = 0, bs = 2;
    for (int s = 0; s < 7; ++s) {
        asm volatile("s_waitcnt vmcnt(3)" ::: "memory");
        __builtin_amdgcn_s_barrier();
        const int k2 = (s + 2) << 5;
        if (k2 < 256) STAGE(bs, k2);
        __builtin_amdgcn_sched_barrier(0);
        COMPUTE(bc);
        bc = (bc == 2) ? 0 : bc + 1;
        bs = (bs == 2) ? 0 : bs + 1;
    }
    asm volatile("s_waitcnt vmcnt(0)" ::: "memory");
    __builtin_amdgcn_s_barrier();
    COMPUTE(bc);

    // ---- fused epilogue: row stats -> LN -> ReLU -> residual ----
    float bv[4], gv[4], betav[4];
#pragma unroll
    for (int n = 0; n < 4; n++) {
        int col = wn * 64 + n * 16 + fr;
        bv[n] = bias[col];
        gv[n] = g[col];
        betav[n] = b[col];
    }
    // per-(m,r): partial sum/sumsq over this wave's 64 cols; reduce across the 16-lane quarter
#pragma unroll
    for (int m = 0; m < 4; m++) {
#pragma unroll
        for (int r = 0; r < 4; r++) {
            float s = 0.f, q2 = 0.f;
#pragma unroll
            for (int n = 0; n < 4; n++) {
                float z = acc[m][n][r] + bv[n];
                s += z;
                q2 += z * z;
            }
#pragma unroll
            for (int off = 1; off < 16; off <<= 1) {
                s += __shfl_xor(s, off);
                q2 += __shfl_xor(q2, off);
            }
            if (fr == 0) {
                int rl = wr * 64 + m * 16 + kg * 4 + r;
                red_s[rl][wn] = s;
                red_q[rl][wn] = q2;
            }
        }
    }
    __syncthreads();
#pragma unroll
    for (int m = 0; m < 4; m++) {
#pragma unroll
        for (int r = 0; r < 4; r++) {
            const int rl = wr * 64 + m * 16 + kg * 4 + r;
            const long rr = row0 + rl;
            float S = red_s[rl][0] + red_s[rl][1] + red_s[rl][2] + red_s[rl][3];
            float Q = red_q[rl][0] + red_q[rl][1] + red_q[rl][2] + red_q[rl][3];
            float mean = S * (1.f / 256.f);
            float var = Q * (1.f / 256.f) - mean * mean;
            float inv = rsqrtf(var + 1e-5f);
            if (rr < M) {
#pragma unroll
                for (int n = 0; n < 4; n++) {
                    int col = wn * 64 + n * 16 + fr;
                    float z = acc[m][n][r] + bv[n];
                    long idx = rr * 256 + col;
                    float o = hf[idx] + fmaxf((z - mean) * inv * gv[n] + betav[n], 0.f);
                    hf[idx] = o;
                    hb[idx] = f2bf(o);
                }
            }
        }
    }
}

// ---------------- host orchestration ----------------
extern "C" void kernel_launch(void* const* d_in, const int* in_sizes, int n_in,
                              void* d_out, int out_size, void* d_ws, size_t ws_size,
                              hipStream_t stream) {
    const float* x    = (const float*)d_in[0];
    const int*   eidx = (const int*)d_in[1];
    const float* ln_g = (const float*)d_in[2];
    const float* ln_b = (const float*)d_in[3];
    const float* W1   = (const float*)d_in[4];
    const float* b1   = (const float*)d_in[5];
    const float* W2   = (const float*)d_in[6];
    const float* b2   = (const float*)d_in[7];
    const float* Wa   = (const float*)d_in[8];
    const float* ba   = (const float*)d_in[9];
    const float* Wb   = (const float*)d_in[10];
    const float* bb   = (const float*)d_in[11];
    const float* ng   = (const float*)d_in[12];
    const float* nbt  = (const float*)d_in[13];
    const float* Wd1  = (const float*)d_in[14];
    const float* bd1  = (const float*)d_in[15];
    const float* Wd2  = (const float*)d_in[16];
    const float* bd2  = (const float*)d_in[17];
    const float* outg = (const float*)d_in[18];
    const float* outbeta = (const float*)d_in[19];
    float* out = (float*)d_out;

    const int N = in_sizes[0] / 1024;  // 50000
    const int E = in_sizes[1] / 2;     // 800000
    const int* e_src = eidx;
    const int* e_dst = eidx + E;

    char* ws = (char*)d_ws;
    size_t off = 0;
    auto alloc = [&](size_t bytes) -> char* {
        char* p = ws + off;
        off += (bytes + 255) & ~(size_t)255;
        return p;
    };

    // big multiplexed region: xln (N x 1024 bf16), later {z | za}, finally delta
    unsigned short* xln = (unsigned short*)alloc((size_t)N * 1024 * 2);
    unsigned short* zb16 = xln;                                          // N*256 bf16
    unsigned short* za   = (unsigned short*)((char*)xln + (size_t)N * 256 * 2);  // N*256 bf16
    unsigned short* delta = xln;                                         // N*1024 bf16

    unsigned short* h1 = (unsigned short*)alloc((size_t)N * 512 * 2);    // also d1
    float*          hf = (float*)alloc((size_t)N * 256 * 4);
    unsigned short* hb = (unsigned short*)alloc((size_t)N * 256 * 2);

    unsigned short* W1T  = (unsigned short*)alloc((size_t)512 * 1024 * 2);
    unsigned short* W2T  = (unsigned short*)alloc((size_t)256 * 512 * 2);
    unsigned short* WaT  = (unsigned short*)alloc((size_t)3 * 256 * 256 * 2);
    unsigned short* WbT  = (unsigned short*)alloc((size_t)3 * 256 * 256 * 2);
    unsigned short* Wd1T = (unsigned short*)alloc((size_t)512 * 256 * 2);
    unsigned short* Wd2T = (unsigned short*)alloc((size_t)1024 * 512 * 2);

    int* deg  = (int*)alloc((size_t)(N + 1) * 4);
    int* rp   = (int*)alloc((size_t)(N + 1) * 4);
    int* cur  = (int*)alloc((size_t)N * 4);
    int* bsum = (int*)alloc(64 * 4);
    int* boff = (int*)alloc(64 * 4);
    int* esrc = (int*)alloc((size_t)E * 4);

    auto cdiv = [](long a, long b) { return (int)((a + b - 1) / b); };

    // weight prep
    k_transpose<<<cdiv((long)1024 * 512, 256), 256, 0, stream>>>(W1, W1T, 1024, 512);
    k_transpose<<<cdiv((long)512 * 256, 256), 256, 0, stream>>>(W2, W2T, 512, 256);
    for (int i = 0; i < 3; i++) {
        k_transpose<<<cdiv(65536, 256), 256, 0, stream>>>(Wa + (size_t)i * 65536, WaT + (size_t)i * 65536, 256, 256);
        k_transpose<<<cdiv(65536, 256), 256, 0, stream>>>(Wb + (size_t)i * 65536, WbT + (size_t)i * 65536, 256, 256);
    }
    k_transpose<<<cdiv((long)256 * 512, 256), 256, 0, stream>>>(Wd1, Wd1T, 256, 512);
    k_transpose<<<cdiv((long)512 * 1024, 256), 256, 0, stream>>>(Wd2, Wd2T, 512, 1024);

    // CSR (built once, reused for all 3 layers)
    k_zero_i32<<<cdiv(N, 256), 256, 0, stream>>>(deg, N);
    k_hist<<<cdiv(E, 256), 256, 0, stream>>>(e_dst, E, deg);
    int nb1 = cdiv(N, 1024);  // 49 (<= 64 required by k_scan2)
    k_scan1<<<nb1, 1024, 0, stream>>>(deg, rp, bsum, N);
    k_scan2<<<1, 64, 0, stream>>>(bsum, boff, nb1);
    k_scan3<<<cdiv(N, 256), 256, 0, stream>>>(rp, boff, cur, N, E);
    k_fill<<<cdiv(E, 256), 256, 0, stream>>>(e_src, e_dst, E, cur, esrc);

    const int ntM = cdiv(N, 128);  // 391

    // in_proj
    k_ln1024_in<<<N, 256, 0, stream>>>(x, ln_g, ln_b, xln);
    k_gemm<1, 1, 0><<<ntM * 4, 256, 0, stream>>>(xln, W1T, b1, N, 1024, 512, h1, nullptr);
    k_gemm<0, 1, 1><<<ntM * 2, 256, 0, stream>>>(h1, W2T, b2, N, 512, 256, hb, hf);

    // GNN blocks: agg -> GEMM-A (relu) -> fused GEMM-B + LN + ReLU + residual
    for (int i = 0; i < 3; i++) {
        k_agg<<<cdiv(N, 4), 256, 0, stream>>>(hf, hb, rp, esrc, zb16, N);
        k_gemm<1, 1, 0><<<ntM * 2, 256, 0, stream>>>(zb16, WaT + (size_t)i * 65536, ba + (size_t)i * 256,
                                                     N, 256, 256, za, nullptr);
        k_gemm_fused_ln<<<ntM, 512, 0, stream>>>(za, WbT + (size_t)i * 65536, bb + (size_t)i * 256,
                                                 ng + (size_t)i * 256, nbt + (size_t)i * 256,
                                                 hf, hb, N);
    }

    // delta_proj + output LN
    k_gemm<1, 1, 0><<<ntM * 4, 256, 0, stream>>>(hb, Wd1T, bd1, N, 256, 512, h1, nullptr);
    k_gemm<0, 1, 0><<<ntM * 8, 256, 0, stream>>>(h1, Wd2T, bd2, N, 512, 1024, delta, nullptr);
    k_ln1024_out<<<N, 256, 0, stream>>>(x, delta, outg, outbeta, out);
}

// Round 8
// 987.840 us; speedup vs baseline: 1.3098x; 1.1117x over previous
//
#include <hip/hip_runtime.h>
#include <hip/hip_bf16.h>

#define DEVI __device__ __forceinline__

using bf16x8 = __attribute__((ext_vector_type(8))) short;   // 8 bf16 in 4 VGPRs (per guide §3)
using f32x4  = __attribute__((ext_vector_type(4))) float;

DEVI unsigned short f2bf(float f) {
    unsigned u = __builtin_bit_cast(unsigned, f);
    return (unsigned short)((u + 0x7FFFu + ((u >> 16) & 1u)) >> 16);
}
DEVI float bf2f(unsigned short h) {
    return __builtin_bit_cast(float, (unsigned)h << 16);
}

DEVI f32x4 mfma16(bf16x8 a, bf16x8 b, f32x4 c) {
    return __builtin_amdgcn_mfma_f32_16x16x32_bf16(a, b, c, 0, 0, 0);
}

// async global->LDS, 16B per lane, LDS dest = wave-uniform base + lane*16 (guide §5)
DEVI void gl16(const void* g, void* l) {
    __builtin_amdgcn_global_load_lds((const __attribute__((address_space(1))) void*)g,
                                     (__attribute__((address_space(3))) void*)l,
                                     16, 0, 0);
}

// ---------------- ALL weight transposes + bf16 cast in ONE launch ----------------
// WT[n*K+k] = W[k*N+n]; segment table is compile-time (shapes fixed by the model).
// total elems = 524288 + 131072 + 196608 + 196608 + 131072 + 524288 = 1703936 = 6656*256
__global__ void k_transpose_all(const float* __restrict__ W1, const float* __restrict__ W2,
                                const float* __restrict__ Wa, const float* __restrict__ Wb,
                                const float* __restrict__ Wd1, const float* __restrict__ Wd2,
                                unsigned short* __restrict__ W1T, unsigned short* __restrict__ W2T,
                                unsigned short* __restrict__ WaT, unsigned short* __restrict__ WbT,
                                unsigned short* __restrict__ Wd1T, unsigned short* __restrict__ Wd2T) {
    long i = (long)blockIdx.x * 256 + threadIdx.x;
    if (i < 524288) {                      // W1T: [512][1024] <- W1 [1024][512]
        int nn = (int)(i >> 10), kk = (int)(i & 1023);
        W1T[i] = f2bf(W1[(long)kk * 512 + nn]);
        return;
    }
    i -= 524288;
    if (i < 131072) {                      // W2T: [256][512] <- W2 [512][256]
        int nn = (int)(i >> 9), kk = (int)(i & 511);
        W2T[i] = f2bf(W2[(long)kk * 256 + nn]);
        return;
    }
    i -= 131072;
    if (i < 196608) {                      // WaT: 3 x [256][256]
        int li = (int)(i & 65535), layer = (int)(i >> 16);
        int nn = li >> 8, kk = li & 255;
        WaT[i] = f2bf(Wa[(long)layer * 65536 + (long)kk * 256 + nn]);
        return;
    }
    i -= 196608;
    if (i < 196608) {                      // WbT: 3 x [256][256]
        int li = (int)(i & 65535), layer = (int)(i >> 16);
        int nn = li >> 8, kk = li & 255;
        WbT[i] = f2bf(Wb[(long)layer * 65536 + (long)kk * 256 + nn]);
        return;
    }
    i -= 196608;
    if (i < 131072) {                      // Wd1T: [512][256] <- Wd1 [256][512]
        int nn = (int)(i >> 8), kk = (int)(i & 255);
        Wd1T[i] = f2bf(Wd1[(long)kk * 512 + nn]);
        return;
    }
    i -= 131072;
    if (i < 524288) {                      // Wd2T: [1024][512] <- Wd2 [512][1024]
        int nn = (int)(i >> 9), kk = (int)(i & 511);
        Wd2T[i] = f2bf(Wd2[(long)kk * 1024 + nn]);
    }
}

// ---------------- CSR build ----------------
__global__ void k_zero_i32(int* p, int n) {
    int i = blockIdx.x * 256 + threadIdx.x;
    if (i < n) p[i] = 0;
}
__global__ void k_hist(const int* __restrict__ dst, int E, int* __restrict__ deg) {
    int i = blockIdx.x * 256 + threadIdx.x;
    if (i < E) atomicAdd(&deg[dst[i]], 1);
}
__global__ __launch_bounds__(1024)
void k_scan1(const int* __restrict__ deg, int* __restrict__ rp, int* __restrict__ bsum, int n) {
    __shared__ int sh[1024];
    int t = threadIdx.x;
    int i = blockIdx.x * 1024 + t;
    int v = (i < n) ? deg[i] : 0;
    sh[t] = v;
    __syncthreads();
    for (int off = 1; off < 1024; off <<= 1) {
        int y = (t >= off) ? sh[t - off] : 0;
        __syncthreads();
        sh[t] += y;
        __syncthreads();
    }
    if (i < n) rp[i] = sh[t] - v;            // exclusive within block
    if (t == 1023) bsum[blockIdx.x] = sh[1023];
}
__global__ __launch_bounds__(64)
void k_scan2(const int* __restrict__ bsum, int* __restrict__ boff, int nb) {  // nb <= 64
    int lane = threadIdx.x;
    int v = (lane < nb) ? bsum[lane] : 0;
    int x = v;
    for (int off = 1; off < 64; off <<= 1) {
        int y = __shfl_up(x, off);
        if (lane >= off) x += y;
    }
    if (lane < nb) boff[lane] = x - v;
}
__global__ void k_scan3(int* __restrict__ rp, const int* __restrict__ boff,
                        int* __restrict__ cur, int n, int E) {
    int i = blockIdx.x * 256 + threadIdx.x;
    if (i < n) {
        int v = rp[i] + boff[i >> 10];
        rp[i] = v;
        cur[i] = v;
    }
    if (i == 0) rp[n] = E;
}
__global__ void k_fill(const int* __restrict__ src, const int* __restrict__ dst, int E,
                       int* __restrict__ cur, int* __restrict__ esrc) {
    int i = blockIdx.x * 256 + threadIdx.x;
    if (i < E) {
        int d = dst[i];
        int p = atomicAdd(&cur[d], 1);
        esrc[p] = src[i];
    }
}

// ---------------- LayerNorm kernels ----------------
__global__ __launch_bounds__(256)
void k_ln1024_in(const float* __restrict__ x, const float* __restrict__ g,
                 const float* __restrict__ b, unsigned short* __restrict__ out) {
    const long row = blockIdx.x;
    const int tid = threadIdx.x, lane = tid & 63, wid = tid >> 6;
    float4 v = ((const float4*)(x + row * 1024))[tid];
    float s = v.x + v.y + v.z + v.w;
    float s2 = v.x * v.x + v.y * v.y + v.z * v.z + v.w * v.w;
    for (int off = 1; off < 64; off <<= 1) { s += __shfl_xor(s, off); s2 += __shfl_xor(s2, off); }
    __shared__ float red[8];
    if (lane == 0) { red[wid] = s; red[4 + wid] = s2; }
    __syncthreads();
    s = red[0] + red[1] + red[2] + red[3];
    s2 = red[4] + red[5] + red[6] + red[7];
    float m = s * (1.f / 1024.f);
    float var = s2 * (1.f / 1024.f) - m * m;
    float inv = rsqrtf(var + 1e-5f);
    float4 gv = ((const float4*)g)[tid];
    float4 bv = ((const float4*)b)[tid];
    ushort4 o = make_ushort4(f2bf((v.x - m) * inv * gv.x + bv.x),
                             f2bf((v.y - m) * inv * gv.y + bv.y),
                             f2bf((v.z - m) * inv * gv.z + bv.z),
                             f2bf((v.w - m) * inv * gv.w + bv.w));
    ((ushort4*)(out + row * 1024))[tid] = o;
}

__global__ __launch_bounds__(256)
void k_ln1024_out(const float* __restrict__ x, const unsigned short* __restrict__ delta,
                  const float* __restrict__ g, const float* __restrict__ b,
                  float* __restrict__ out) {
    const long row = blockIdx.x;
    const int tid = threadIdx.x, lane = tid & 63, wid = tid >> 6;
    float4 xv = ((const float4*)(x + row * 1024))[tid];
    ushort4 dv = ((const ushort4*)(delta + row * 1024))[tid];
    float4 v;
    v.x = xv.x + bf2f(dv.x);
    v.y = xv.y + bf2f(dv.y);
    v.z = xv.z + bf2f(dv.z);
    v.w = xv.w + bf2f(dv.w);
    float s = v.x + v.y + v.z + v.w;
    float s2 = v.x * v.x + v.y * v.y + v.z * v.z + v.w * v.w;
    for (int off = 1; off < 64; off <<= 1) { s += __shfl_xor(s, off); s2 += __shfl_xor(s2, off); }
    __shared__ float red[8];
    if (lane == 0) { red[wid] = s; red[4 + wid] = s2; }
    __syncthreads();
    s = red[0] + red[1] + red[2] + red[3];
    s2 = red[4] + red[5] + red[6] + red[7];
    float m = s * (1.f / 1024.f);
    float var = s2 * (1.f / 1024.f) - m * m;
    float inv = rsqrtf(var + 1e-5f);
    float4 gv = ((const float4*)g)[tid];
    float4 bv = ((const float4*)b)[tid];
    float4 o;
    o.x = (v.x - m) * inv * gv.x + bv.x;
    o.y = (v.y - m) * inv * gv.y + bv.y;
    o.z = (v.z - m) * inv * gv.z + bv.z;
    o.w = (v.w - m) * inv * gv.w + bv.w;
    ((float4*)(out + row * 1024))[tid] = o;
}

// ---------------- aggregation: z[dst] = h[dst] + sum_{src in-edges} h[src] ----------------
// one wave per destination node. Edge loop unrolled x4: 4 independent esrc loads + 4
// independent 512B gathers in flight per iteration (4x the per-wave MLP vs serial chain).
__global__ __launch_bounds__(256)
void k_agg(const float* __restrict__ hf, const unsigned short* __restrict__ hb,
           const int* __restrict__ rp, const int* __restrict__ esrc,
           unsigned short* __restrict__ z, int n) {
    int node = blockIdx.x * 4 + (threadIdx.x >> 6);
    if (node >= n) return;
    int lane = threadIdx.x & 63;
    float4 sv = ((const float4*)(hf + (long)node * 256))[lane];
    float a0 = sv.x, a1 = sv.y, a2 = sv.z, a3 = sv.w;
    int beg = rp[node], end = rp[node + 1];
    int e = beg;
    for (; e + 4 <= end; e += 4) {
        int s0 = esrc[e], s1 = esrc[e + 1], s2 = esrc[e + 2], s3 = esrc[e + 3];
        ushort4 v0 = ((const ushort4*)(hb + (long)s0 * 256))[lane];
        ushort4 v1 = ((const ushort4*)(hb + (long)s1 * 256))[lane];
        ushort4 v2 = ((const ushort4*)(hb + (long)s2 * 256))[lane];
        ushort4 v3 = ((const ushort4*)(hb + (long)s3 * 256))[lane];
        a0 += bf2f(v0.x) + bf2f(v1.x) + bf2f(v2.x) + bf2f(v3.x);
        a1 += bf2f(v0.y) + bf2f(v1.y) + bf2f(v2.y) + bf2f(v3.y);
        a2 += bf2f(v0.z) + bf2f(v1.z) + bf2f(v2.z) + bf2f(v3.z);
        a3 += bf2f(v0.w) + bf2f(v1.w) + bf2f(v2.w) + bf2f(v3.w);
    }
    for (; e < end; ++e) {
        int s = esrc[e];
        ushort4 hv = ((const ushort4*)(hb + (long)s * 256))[lane];
        a0 += bf2f(hv.x);
        a1 += bf2f(hv.y);
        a2 += bf2f(hv.z);
        a3 += bf2f(hv.w);
    }
    ushort4 o = make_ushort4(f2bf(a0), f2bf(a1), f2bf(a2), f2bf(a3));
    ((ushort4*)(z + (long)node * 256))[lane] = o;
}

// ---------------- bf16 MFMA GEMM: C[M,Nc] = act(A[M,K] @ W + bias), W given as WT[Nc,K] ----
// 128x128 tile, BK=32, 4 waves (2x2). Proven r3 schedule: 3 LDS buffers, depth-2 prefetch,
// per K-step vmcnt(4) + one barrier.
template <int RELU, int WB, int WF>
__global__ __launch_bounds__(256)
void k_gemm(const unsigned short* __restrict__ A, const unsigned short* __restrict__ WT,
            const float* __restrict__ bias, int M, int K, int Nc,
            unsigned short* __restrict__ outb, float* __restrict__ outf) {
    __shared__ __align__(16) unsigned short lds_a[3 * 4096];
    __shared__ __align__(16) unsigned short lds_b[3 * 4096];
    const int tid = threadIdx.x;
    const int wid = tid >> 6, lane = tid & 63;

    // bijective XCD swizzle (8 XCDs, round-robin dispatch; guide T1/m204)
    const int nwg = gridDim.x;
    const int q = nwg >> 3, r8 = nwg & 7;
    const int xcd = blockIdx.x & 7, sl = blockIdx.x >> 3;
    const int bid = (xcd < r8 ? xcd * (q + 1) : r8 * (q + 1) + (xcd - r8) * q) + sl;

    const int ntN = Nc >> 7;
    const int tM = bid / ntN, tN = bid - tM * ntN;
    const long row0 = (long)tM * 128;
    const int col0 = tN << 7;
    const int wr = wid >> 1, wc = wid & 1;

    const int sr = tid >> 2;
    const int sc = (((tid & 3) ^ ((sr >> 2) & 3)) << 3);
    long ra0 = row0 + sr;       if (ra0 > (long)M - 1) ra0 = M - 1;
    long ra1 = row0 + sr + 64;  if (ra1 > (long)M - 1) ra1 = M - 1;
    const unsigned short* pa0 = A + ra0 * K + sc;
    const unsigned short* pa1 = A + ra1 * K + sc;
    const unsigned short* pb0 = WT + (long)(col0 + sr) * K + sc;
    const unsigned short* pb1 = WT + (long)(col0 + sr + 64) * K + sc;

    f32x4 zero4 = {0.f, 0.f, 0.f, 0.f};
    f32x4 acc[4][4];
#pragma unroll
    for (int m = 0; m < 4; m++)
#pragma unroll
        for (int n = 0; n < 4; n++) acc[m][n] = zero4;

    const int fr = lane & 15, kg = lane >> 4;
    const int s4 = kg ^ ((fr >> 2) & 3);
    const unsigned short* la = &lds_a[(wr * 64 + fr) * 32 + s4 * 8];
    const unsigned short* lb = &lds_b[(wc * 64 + fr) * 32 + s4 * 8];

    auto STAGE = [&](int buf, int k0) {
        const int o = buf << 12;
        gl16(pa0 + k0, &lds_a[o + wid * 512]);
        gl16(pa1 + k0, &lds_a[o + 2048 + wid * 512]);
        gl16(pb0 + k0, &lds_b[o + wid * 512]);
        gl16(pb1 + k0, &lds_b[o + 2048 + wid * 512]);
    };
    auto COMPUTE = [&](int buf) {
        const int o = buf << 12;
        bf16x8 af[4], bfr[4];
#pragma unroll
        for (int m = 0; m < 4; m++) af[m] = *(const bf16x8*)(la + o + m * 16 * 32);
#pragma unroll
        for (int n = 0; n < 4; n++) bfr[n] = *(const bf16x8*)(lb + o + n * 16 * 32);
#pragma unroll
        for (int m = 0; m < 4; m++)
#pragma unroll
            for (int n = 0; n < 4; n++) acc[m][n] = mfma16(af[m], bfr[n], acc[m][n]);
    };

    const int nsteps = K >> 5;
    STAGE(0, 0);
    STAGE(1, 32);

    int bc = 0, bs = 2;
    for (int s = 0; s < nsteps - 1; ++s) {
        asm volatile("s_waitcnt vmcnt(4)" ::: "memory");
        __builtin_amdgcn_s_barrier();
        const int k2 = (s + 2) << 5;
        if (k2 < K) STAGE(bs, k2);
        __builtin_amdgcn_sched_barrier(0);
        COMPUTE(bc);
        bc = (bc == 2) ? 0 : bc + 1;
        bs = (bs == 2) ? 0 : bs + 1;
    }
    asm volatile("s_waitcnt vmcnt(0)" ::: "memory");
    __builtin_amdgcn_s_barrier();
    COMPUTE(bc);

#pragma unroll
    for (int n = 0; n < 4; n++) {
        int col = col0 + wc * 64 + n * 16 + fr;
        float bv = bias[col];
#pragma unroll
        for (int m = 0; m < 4; m++) {
            long rb = row0 + wr * 64 + m * 16 + kg * 4;
#pragma unroll
            for (int r = 0; r < 4; r++) {
                long rr = rb + r;
                if (rr < M) {
                    float v = acc[m][n][r] + bv;
                    if (RELU) v = fmaxf(v, 0.f);
                    long idx = rr * Nc + col;
                    if (WB) outb[idx] = f2bf(v);
                    if (WF) outf[idx] = v;
                }
            }
        }
    }
}

// ---------------- fused layer-B GEMM + LayerNorm(256) + ReLU + residual ----------------
// C = za @ Wb + bb  -> z = relu(LN(C)) -> hf += z (fp32), hb = bf16(hf).
// BM=128, BN=256=Nc (block owns FULL rows -> row-LN in epilogue), K=256 fixed.
// 8 waves (2Mx4N), per-wave 64x64 tile; same 3-buf depth-2 counted-vmcnt schedule.
__global__ __launch_bounds__(512)
void k_gemm_fused_ln(const unsigned short* __restrict__ A, const unsigned short* __restrict__ WT,
                     const float* __restrict__ bias, const float* __restrict__ g,
                     const float* __restrict__ b, float* __restrict__ hf,
                     unsigned short* __restrict__ hb, int M) {
    __shared__ __align__(16) unsigned short lds_a[3 * 4096];   // 3 x [128][32]
    __shared__ __align__(16) unsigned short lds_b[3 * 8192];   // 3 x [256][32]
    __shared__ float red_s[128][4];
    __shared__ float red_q[128][4];
    const int tid = threadIdx.x, wid = tid >> 6, lane = tid & 63;
    const int fr = lane & 15, kg = lane >> 4;

    // bijective XCD swizzle
    const int nwg = gridDim.x;
    const int q = nwg >> 3, r8 = nwg & 7;
    const int xcd = blockIdx.x & 7, sl = blockIdx.x >> 3;
    const int bid = (xcd < r8 ? xcd * (q + 1) : r8 * (q + 1) + (xcd - r8) * q) + sl;
    const long row0 = (long)bid * 128;
    const int wr = wid >> 2, wn = wid & 3;

    const int srow = lane >> 2, slot = lane & 3;
    long ar = row0 + wid * 16 + srow; if (ar > (long)M - 1) ar = M - 1;
    const unsigned short* pa  = A + ar * 256 + slot * 8;
    const unsigned short* pb0 = WT + (long)(wid * 16 + srow) * 256 + slot * 8;
    const unsigned short* pb1 = WT + (long)(128 + wid * 16 + srow) * 256 + slot * 8;

    f32x4 zero4 = {0.f, 0.f, 0.f, 0.f};
    f32x4 acc[4][4];
#pragma unroll
    for (int m = 0; m < 4; m++)
#pragma unroll
        for (int n = 0; n < 4; n++) acc[m][n] = zero4;

    auto STAGE = [&](int buf, int k0) {
        gl16(pa + k0, &lds_a[buf * 4096 + wid * 512]);
        gl16(pb0 + k0, &lds_b[buf * 8192 + wid * 512]);
        gl16(pb1 + k0, &lds_b[buf * 8192 + 4096 + wid * 512]);
    };
    auto COMPUTE = [&](int buf) {
        bf16x8 af[4], bfr[4];
#pragma unroll
        for (int m = 0; m < 4; m++)
            af[m] = *(const bf16x8*)&lds_a[buf * 4096 + (wr * 64 + m * 16 + fr) * 32 + kg * 8];
#pragma unroll
        for (int n = 0; n < 4; n++)
            bfr[n] = *(const bf16x8*)&lds_b[buf * 8192 + (wn * 64 + n * 16 + fr) * 32 + kg * 8];
#pragma unroll
        for (int m = 0; m < 4; m++)
#pragma unroll
            for (int n = 0; n < 4; n++) acc[m][n] = mfma16(af[m], bfr[n], acc[m][n]);
    };

    // K=256 -> 8 steps
    STAGE(0, 0);
    STAGE(1, 32);
    int bc = 0, bs = 2;
    for (int s = 0; s < 7; ++s) {
        asm volatile("s_waitcnt vmcnt(3)" ::: "memory");
        __builtin_amdgcn_s_barrier();
        const int k2 = (s + 2) << 5;
        if (k2 < 256) STAGE(bs, k2);
        __builtin_amdgcn_sched_barrier(0);
        COMPUTE(bc);
        bc = (bc == 2) ? 0 : bc + 1;
        bs = (bs == 2) ? 0 : bs + 1;
    }
    asm volatile("s_waitcnt vmcnt(0)" ::: "memory");
    __builtin_amdgcn_s_barrier();
    COMPUTE(bc);

    // ---- fused epilogue: row stats -> LN -> ReLU -> residual ----
    float bv[4], gv[4], betav[4];
#pragma unroll
    for (int n = 0; n < 4; n++) {
        int col = wn * 64 + n * 16 + fr;
        bv[n] = bias[col];
        gv[n] = g[col];
        betav[n] = b[col];
    }
#pragma unroll
    for (int m = 0; m < 4; m++) {
#pragma unroll
        for (int r = 0; r < 4; r++) {
            float s = 0.f, q2 = 0.f;
#pragma unroll
            for (int n = 0; n < 4; n++) {
                float z = acc[m][n][r] + bv[n];
                s += z;
                q2 += z * z;
            }
#pragma unroll
            for (int off = 1; off < 16; off <<= 1) {
                s += __shfl_xor(s, off);
                q2 += __shfl_xor(q2, off);
            }
            if (fr == 0) {
                int rl = wr * 64 + m * 16 + kg * 4 + r;
                red_s[rl][wn] = s;
                red_q[rl][wn] = q2;
            }
        }
    }
    __syncthreads();
#pragma unroll
    for (int m = 0; m < 4; m++) {
#pragma unroll
        for (int r = 0; r < 4; r++) {
            const int rl = wr * 64 + m * 16 + kg * 4 + r;
            const long rr = row0 + rl;
            float S = red_s[rl][0] + red_s[rl][1] + red_s[rl][2] + red_s[rl][3];
            float Q = red_q[rl][0] + red_q[rl][1] + red_q[rl][2] + red_q[rl][3];
            float mean = S * (1.f / 256.f);
            float var = Q * (1.f / 256.f) - mean * mean;
            float inv = rsqrtf(var + 1e-5f);
            if (rr < M) {
#pragma unroll
                for (int n = 0; n < 4; n++) {
                    int col = wn * 64 + n * 16 + fr;
                    float z = acc[m][n][r] + bv[n];
                    long idx = rr * 256 + col;
                    float o = hf[idx] + fmaxf((z - mean) * inv * gv[n] + betav[n], 0.f);
                    hf[idx] = o;
                    hb[idx] = f2bf(o);
                }
            }
        }
    }
}

// ---------------- host orchestration ----------------
extern "C" void kernel_launch(void* const* d_in, const int* in_sizes, int n_in,
                              void* d_out, int out_size, void* d_ws, size_t ws_size,
                              hipStream_t stream) {
    const float* x    = (const float*)d_in[0];
    const int*   eidx = (const int*)d_in[1];
    const float* ln_g = (const float*)d_in[2];
    const float* ln_b = (const float*)d_in[3];
    const float* W1   = (const float*)d_in[4];
    const float* b1   = (const float*)d_in[5];
    const float* W2   = (const float*)d_in[6];
    const float* b2   = (const float*)d_in[7];
    const float* Wa   = (const float*)d_in[8];
    const float* ba   = (const float*)d_in[9];
    const float* Wb   = (const float*)d_in[10];
    const float* bb   = (const float*)d_in[11];
    const float* ng   = (const float*)d_in[12];
    const float* nbt  = (const float*)d_in[13];
    const float* Wd1  = (const float*)d_in[14];
    const float* bd1  = (const float*)d_in[15];
    const float* Wd2  = (const float*)d_in[16];
    const float* bd2  = (const float*)d_in[17];
    const float* outg = (const float*)d_in[18];
    const float* outbeta = (const float*)d_in[19];
    float* out = (float*)d_out;

    const int N = in_sizes[0] / 1024;  // 50000
    const int E = in_sizes[1] / 2;     // 800000
    const int* e_src = eidx;
    const int* e_dst = eidx + E;

    char* ws = (char*)d_ws;
    size_t off = 0;
    auto alloc = [&](size_t bytes) -> char* {
        char* p = ws + off;
        off += (bytes + 255) & ~(size_t)255;
        return p;
    };

    // big multiplexed region: xln (N x 1024 bf16), later {z | za}, finally delta
    unsigned short* xln = (unsigned short*)alloc((size_t)N * 1024 * 2);
    unsigned short* zb16 = xln;                                          // N*256 bf16
    unsigned short* za   = (unsigned short*)((char*)xln + (size_t)N * 256 * 2);  // N*256 bf16
    unsigned short* delta = xln;                                         // N*1024 bf16

    unsigned short* h1 = (unsigned short*)alloc((size_t)N * 512 * 2);    // also d1
    float*          hf = (float*)alloc((size_t)N * 256 * 4);
    unsigned short* hb = (unsigned short*)alloc((size_t)N * 256 * 2);

    unsigned short* W1T  = (unsigned short*)alloc((size_t)512 * 1024 * 2);
    unsigned short* W2T  = (unsigned short*)alloc((size_t)256 * 512 * 2);
    unsigned short* WaT  = (unsigned short*)alloc((size_t)3 * 256 * 256 * 2);
    unsigned short* WbT  = (unsigned short*)alloc((size_t)3 * 256 * 256 * 2);
    unsigned short* Wd1T = (unsigned short*)alloc((size_t)512 * 256 * 2);
    unsigned short* Wd2T = (unsigned short*)alloc((size_t)1024 * 512 * 2);

    int* deg  = (int*)alloc((size_t)(N + 1) * 4);
    int* rp   = (int*)alloc((size_t)(N + 1) * 4);
    int* cur  = (int*)alloc((size_t)N * 4);
    int* bsum = (int*)alloc(64 * 4);
    int* boff = (int*)alloc(64 * 4);
    int* esrc = (int*)alloc((size_t)E * 4);

    auto cdiv = [](long a, long b) { return (int)((a + b - 1) / b); };

    // weight prep: ONE launch for all transposes (1703936 elems = 6656 blocks)
    k_transpose_all<<<6656, 256, 0, stream>>>(W1, W2, Wa, Wb, Wd1, Wd2,
                                              W1T, W2T, WaT, WbT, Wd1T, Wd2T);

    // CSR (built once, reused for all 3 layers)
    k_zero_i32<<<cdiv(N, 256), 256, 0, stream>>>(deg, N);
    k_hist<<<cdiv(E, 256), 256, 0, stream>>>(e_dst, E, deg);
    int nb1 = cdiv(N, 1024);  // 49 (<= 64 required by k_scan2)
    k_scan1<<<nb1, 1024, 0, stream>>>(deg, rp, bsum, N);
    k_scan2<<<1, 64, 0, stream>>>(bsum, boff, nb1);
    k_scan3<<<cdiv(N, 256), 256, 0, stream>>>(rp, boff, cur, N, E);
    k_fill<<<cdiv(E, 256), 256, 0, stream>>>(e_src, e_dst, E, cur, esrc);

    const int ntM = cdiv(N, 128);  // 391

    // in_proj
    k_ln1024_in<<<N, 256, 0, stream>>>(x, ln_g, ln_b, xln);
    k_gemm<1, 1, 0><<<ntM * 4, 256, 0, stream>>>(xln, W1T, b1, N, 1024, 512, h1, nullptr);
    k_gemm<0, 1, 1><<<ntM * 2, 256, 0, stream>>>(h1, W2T, b2, N, 512, 256, hb, hf);

    // GNN blocks: agg -> GEMM-A (relu) -> fused GEMM-B + LN + ReLU + residual
    for (int i = 0; i < 3; i++) {
        k_agg<<<cdiv(N, 4), 256, 0, stream>>>(hf, hb, rp, esrc, zb16, N);
        k_gemm<1, 1, 0><<<ntM * 2, 256, 0, stream>>>(zb16, WaT + (size_t)i * 65536, ba + (size_t)i * 256,
                                                     N, 256, 256, za, nullptr);
        k_gemm_fused_ln<<<ntM, 512, 0, stream>>>(za, WbT + (size_t)i * 65536, bb + (size_t)i * 256,
                                                 ng + (size_t)i * 256, nbt + (size_t)i * 256,
                                                 hf, hb, N);
    }

    // delta_proj + output LN
    k_gemm<1, 1, 0><<<ntM * 4, 256, 0, stream>>>(hb, Wd1T, bd1, N, 256, 512, h1, nullptr);
    k_gemm<0, 1, 0><<<ntM * 8, 256, 0, stream>>>(h1, Wd2T, bd2, N, 512, 1024, delta, nullptr);
    k_ln1024_out<<<N, 256, 0, stream>>>(x, delta, outg, outbeta, out);
}